// Round 11
// baseline (1978.648 us; speedup 1.0000x reference)
//
#include <hip/hip_runtime.h>

#define B_ 4
#define T_ 250
#define U_ 120
#define D_ 512
#define G_ 2048   // 4*D (gates)
#define O_ 1024   // odim
#define NBLK 256

typedef __attribute__((ext_vector_type(8))) short bf16x8;
typedef __attribute__((ext_vector_type(4))) float f32x4;
typedef __attribute__((ext_vector_type(4))) unsigned int ui4;

__device__ __forceinline__ float tanh_fast(float x){
  float e = __expf(2.f*x);
  return 1.f - 2.f/(e + 1.f);
}
__device__ __forceinline__ float sigmoid_fast(float x){
  return 1.f/(1.f + __expf(-x));
}
__device__ __forceinline__ unsigned short f2bf(float x){
  unsigned int u = __float_as_uint(x);
  unsigned int r = (u + 0x7FFFu + ((u >> 16) & 1u)) >> 16;
  return (unsigned short)r;
}

// MALL-coherent single-value ops
__device__ __forceinline__ void atomStoreF(float* p, float v){
  __hip_atomic_store(p, v, __ATOMIC_RELAXED, __HIP_MEMORY_SCOPE_AGENT);
}
__device__ __forceinline__ void mall_load4f(const float* p0, const float* p1,
    const float* p2, const float* p3, float& v0, float& v1, float& v2, float& v3){
  asm volatile(
    "global_load_dword %0, %4, off sc0 sc1\n\t"
    "global_load_dword %1, %5, off sc0 sc1\n\t"
    "global_load_dword %2, %6, off sc0 sc1\n\t"
    "global_load_dword %3, %7, off sc0 sc1\n\t"
    "s_waitcnt vmcnt(0)"
    : "=&v"(v0), "=&v"(v1), "=&v"(v2), "=&v"(v3)
    : "v"(p0), "v"(p1), "v"(p2), "v"(p3)
    : "memory");
}

// barrier v4: split arrive/wait so independent compute hides the round trips.
__device__ __forceinline__ void gbar_arrive(int* flags, int gen){
  __syncthreads();   // compiler drains each wave's vmcnt before s_barrier
  if (threadIdx.x == 0){
    asm volatile("s_waitcnt vmcnt(0)" ::: "memory");
    __hip_atomic_store(&flags[blockIdx.x*16], gen, __ATOMIC_RELAXED,
                       __HIP_MEMORY_SCOPE_AGENT);
  }
}
__device__ __forceinline__ void gbar_wait(int* flags, int* rel, int gen){
  if (blockIdx.x == 0){
    if (threadIdx.x < 64){
      int l = threadIdx.x;
      const int* p0 = flags + (l*4+0)*16;
      const int* p1 = flags + (l*4+1)*16;
      const int* p2 = flags + (l*4+2)*16;
      const int* p3 = flags + (l*4+3)*16;
      long c = 0;
      while (true){
        int f0,f1,f2,f3;
        asm volatile(
          "global_load_dword %0, %4, off sc0 sc1\n\t"
          "global_load_dword %1, %5, off sc0 sc1\n\t"
          "global_load_dword %2, %6, off sc0 sc1\n\t"
          "global_load_dword %3, %7, off sc0 sc1\n\t"
          "s_waitcnt vmcnt(0)"
          : "=&v"(f0),"=&v"(f1),"=&v"(f2),"=&v"(f3)
          : "v"(p0), "v"(p1), "v"(p2), "v"(p3)
          : "memory");
        int m0 = f0 < f1 ? f0 : f1;
        int m1 = f2 < f3 ? f2 : f3;
        int mm = m0 < m1 ? m0 : m1;
        if (__all(mm >= gen)) break;
        if (++c > (1L<<22)) break;   // anti-hang valve
      }
      if (threadIdx.x == 0)
        __hip_atomic_store(rel, gen, __ATOMIC_RELAXED,
                           __HIP_MEMORY_SCOPE_AGENT);
    }
  } else {
    if (threadIdx.x == 0){
      long c = 0;
      while (__hip_atomic_load(rel, __ATOMIC_RELAXED,
                               __HIP_MEMORY_SCOPE_AGENT) < gen){
        if (++c > (1L<<22)) break;
      }
    }
  }
  __syncthreads();
}
__device__ __forceinline__ void gbar(int* flags, int* rel, int gen){
  gbar_arrive(flags, gen);
  gbar_wait(flags, rel, gen);
}

// gather + flag-init fused (saves a launch)
__global__ void gather_embed_k(const int* __restrict__ ys, const float* __restrict__ embed,
                               float* __restrict__ eys, int* __restrict__ flags){
  int i = blockIdx.x*256 + threadIdx.x;
  if (i < NBLK*16 + 16)
    __hip_atomic_store(&flags[i], 0, __ATOMIC_RELAXED, __HIP_MEMORY_SCOPE_AGENT);
  if (i < B_*U_*D_){
    int r = i >> 9, k = i & 511;
    eys[i] = embed[ys[r]*D_ + k];
  }
}

// ---------- GEMM bodies ----------
__device__ __forceinline__ void gemm64_nt_body(float* smem,
  const float* __restrict__ A, int lda, const float* __restrict__ B, int ldb,
  const float* __restrict__ bias, float* __restrict__ C, int ldc,
  int M, int N, int K, int bx, int by)
{
  float (*As)[65] = (float(*)[65])smem;
  float (*Bs)[65] = (float(*)[65])(smem + 16*65);
  int tid = threadIdx.x;
  int m0 = by*64, n0 = bx*64;
  int tx = tid & 15, ty = tid >> 4;
  float acc[4][4] = {};
  for (int k0 = 0; k0 < K; k0 += 16){
#pragma unroll
    for (int i=0;i<4;i++){
      int e = tid + 256*i;
      int mm = e >> 4, kk = e & 15;
      int mg = m0 + mm;
      As[kk][mm] = (mg < M) ? A[(size_t)mg*lda + k0 + kk] : 0.f;
      int ng = n0 + mm;
      Bs[kk][mm] = (ng < N) ? B[(size_t)ng*ldb + k0 + kk] : 0.f;
    }
    __syncthreads();
#pragma unroll
    for (int kk=0;kk<16;kk++){
      float av[4], bv[4];
#pragma unroll
      for (int i=0;i<4;i++) av[i] = As[kk][ty*4+i];
#pragma unroll
      for (int j=0;j<4;j++) bv[j] = Bs[kk][tx*4+j];
#pragma unroll
      for (int i=0;i<4;i++)
#pragma unroll
        for (int j=0;j<4;j++) acc[i][j] += av[i]*bv[j];
    }
    __syncthreads();
  }
#pragma unroll
  for (int i=0;i<4;i++){
    int m = m0 + ty*4 + i;
    if (m < M){
#pragma unroll
      for (int j=0;j<4;j++){
        int n = n0 + tx*4 + j;
        if (n < N) C[(size_t)m*ldc + n] = acc[i][j] + (bias ? bias[n] : 0.f);
      }
    }
  }
}

// 128x128-tile, 8x8 acc per thread; A read as A[m][k] (nt: B[n][k])
__device__ __forceinline__ void gemm128_nt_body(float* smem,
  const float* __restrict__ A, int lda, const float* __restrict__ B, int ldb,
  const float* __restrict__ bias, float* __restrict__ C, int ldc,
  int M, int N, int K, int bx, int by)
{
  float (*As)[129] = (float(*)[129])smem;
  float (*Bs)[129] = (float(*)[129])(smem + 16*129);
  int tid = threadIdx.x;
  int m0 = by*128, n0 = bx*128;
  int tx = tid & 15, ty = tid >> 4;
  float acc[8][8] = {};
  for (int k0 = 0; k0 < K; k0 += 16){
#pragma unroll
    for (int i=0;i<8;i++){
      int e = tid + 256*i;
      int mm = e >> 4, kk = e & 15;
      int mg = m0 + mm, ng = n0 + mm;
      As[kk][mm] = (mg < M) ? A[(size_t)mg*lda + k0 + kk] : 0.f;
      Bs[kk][mm] = (ng < N) ? B[(size_t)ng*ldb + k0 + kk] : 0.f;
    }
    __syncthreads();
#pragma unroll
    for (int kk=0;kk<16;kk++){
      float av[8], bv[8];
#pragma unroll
      for (int i=0;i<8;i++) av[i] = As[kk][ty*8+i];
#pragma unroll
      for (int j=0;j<8;j++) bv[j] = Bs[kk][tx*8+j];
#pragma unroll
      for (int i=0;i<8;i++)
#pragma unroll
        for (int j=0;j<8;j++) acc[i][j] += av[i]*bv[j];
    }
    __syncthreads();
  }
#pragma unroll
  for (int i=0;i<8;i++){
    int m = m0 + ty*8 + i;
    if (m < M){
#pragma unroll
      for (int j=0;j<8;j++){
        int n = n0 + tx*8 + j;
        if (n < N) C[(size_t)m*ldc + n] = acc[i][j] + (bias ? bias[n] : 0.f);
      }
    }
  }
}

// 128x128-tile nn: B read as B[k][n]
__device__ __forceinline__ void gemm128_nn_body(float* smem,
  const float* __restrict__ A, int lda, const float* __restrict__ B, int ldb,
  const float* __restrict__ bias, float* __restrict__ C, int ldc,
  int M, int N, int K, int bx, int by)
{
  float (*As)[129] = (float(*)[129])smem;
  float (*Bs)[129] = (float(*)[129])(smem + 16*129);
  int tid = threadIdx.x;
  int m0 = by*128, n0 = bx*128;
  int tx = tid & 15, ty = tid >> 4;
  float acc[8][8] = {};
  for (int k0 = 0; k0 < K; k0 += 16){
#pragma unroll
    for (int i=0;i<8;i++){
      int e = tid + 256*i;
      int mm = e >> 4, kk = e & 15;
      int mg = m0 + mm;
      As[kk][mm] = (mg < M) ? A[(size_t)mg*lda + k0 + kk] : 0.f;
      int nn = e & 127, kk2 = e >> 7;
      int ng = n0 + nn;
      Bs[kk2][nn] = (ng < N) ? B[(size_t)(k0+kk2)*ldb + ng] : 0.f;
    }
    __syncthreads();
#pragma unroll
    for (int kk=0;kk<16;kk++){
      float av[8], bv[8];
#pragma unroll
      for (int i=0;i<8;i++) av[i] = As[kk][ty*8+i];
#pragma unroll
      for (int j=0;j<8;j++) bv[j] = Bs[kk][tx*8+j];
#pragma unroll
      for (int i=0;i<8;i++)
#pragma unroll
        for (int j=0;j<8;j++) acc[i][j] += av[i]*bv[j];
    }
    __syncthreads();
  }
#pragma unroll
  for (int i=0;i<8;i++){
    int m = m0 + ty*8 + i;
    if (m < M){
#pragma unroll
      for (int j=0;j<8;j++){
        int n = n0 + tx*8 + j;
        if (n < N) C[(size_t)m*ldc + n] = acc[i][j] + (bias ? bias[n] : 0.f);
      }
    }
  }
}

// fused precompute, 256 blocks exactly:
// [0,32): pre_enc nn 1000x512 | [32,64): henc nt 1000x512
// [64,128): pre0 nt 480x2048  | [128,256): hsW0 nt 1000x2048
__global__ __launch_bounds__(256) void pre_gemms_k(
  const float* __restrict__ hs, const float* __restrict__ eys,
  const float* __restrict__ W_att_enc, const float* __restrict__ b_att_enc,
  const float* __restrict__ W_lin_enc, const float* __restrict__ b_lin_enc,
  const float* __restrict__ W_ih0,
  float* __restrict__ pre_enc, float* __restrict__ henc,
  float* __restrict__ pre0, float* __restrict__ hsW0)
{
  __shared__ float smem[2*16*129];
  int id = blockIdx.x;
  if (id < 32){
    gemm128_nn_body(smem, hs,512, W_att_enc,512, b_att_enc, pre_enc,512,
                    B_*T_,512,512, id & 3, id >> 2);
  } else if (id < 64){
    id -= 32;
    gemm128_nt_body(smem, hs,512, W_lin_enc,512, b_lin_enc, henc,512,
                    B_*T_,512,512, id & 3, id >> 2);
  } else if (id < 128){
    id -= 64;
    gemm128_nt_body(smem, eys,512, W_ih0,1024, nullptr, pre0,2048,
                    B_*U_,2048,512, id & 15, id >> 4);
  } else {
    id -= 128;
    gemm128_nt_body(smem, hs,512, W_ih0+512,1024, nullptr, hsW0,2048,
                    B_*T_,2048,512, id & 15, id >> 4);
  }
}

// standalone nt for hdec (post-scan, small)
__global__ __launch_bounds__(256) void gemm64_nt_k(
  const float* __restrict__ A, int lda, const float* __restrict__ B, int ldb,
  const float* __restrict__ bias, float* __restrict__ C, int ldc,
  int M, int N, int K)
{
  __shared__ float smem[2*16*65];
  gemm64_nt_body(smem, A,lda,B,ldb,bias,C,ldc,M,N,K, blockIdx.x, blockIdx.y);
}

// ---------- LDS-resident scan, barrier v4 + split-wait phase A ----------
__global__ __launch_bounds__(256) void scan_k(
    float* __restrict__ z0, float* __restrict__ z1,
    float* __restrict__ q,  float* __restrict__ e,
    int* __restrict__ flags, int* __restrict__ rel,
    const float* __restrict__ pre_enc, const float* __restrict__ pre0,
    const float* __restrict__ hsW0,
    const float* __restrict__ W_hh0, const float* __restrict__ W_ih1,
    const float* __restrict__ W_hh1, const float* __restrict__ W_att_dec,
    const float* __restrict__ gvec, const int* __restrict__ hlens,
    const float* __restrict__ b_ih0, const float* __restrict__ b_hh0,
    const float* __restrict__ b_ih1, const float* __restrict__ b_hh1,
    float* __restrict__ h_dec)
{
  int bk = blockIdx.x, tid = threadIdx.x;
  int lane = tid & 63, wv = tid >> 6;
  int d0 = bk * 2;

  __shared__ float whh0_s[8*512];   // [gd][k]
  __shared__ float whh1_s[8*512];
  __shared__ float wih1_s[8*512];
  __shared__ float wdec_s[2*512];   // [delta][k]
  __shared__ float hsw_s[4*8*256];  // [b][gd][t(pad 256)]
  __shared__ float pre0_s[480*8];   // [(b*120+u)][gd]
  __shared__ float pre_s[4*512];    // e-rows
  __shared__ float gvec_s[512];
  __shared__ float zs0[2048], zs1[2048], qs[2048];
  __shared__ float pA0[32], pA1[32], gB[32], gC[32];
  __shared__ float bias0_s[8], bias1_s[8], c0_s[8], c1_s[8];
  __shared__ int hlens_s[4];

  // batches this block's e-rows touch (for trimmed q loads)
  int b_lo = (bk*4) / 250;     if (b_lo > 3) b_lo = 3;
  int b_hi = (bk*4 + 3) / 250; if (b_hi > 3) b_hi = 3;

  // ---- one-time LDS load ----
  for (int idx = tid; idx < 8*512; idx += 256){
    int gd = idx >> 9, k = idx & 511;
    int j = (gd >> 1)*512 + d0 + (gd & 1);
    whh0_s[idx] = W_hh0[(size_t)j*512 + k];
    whh1_s[idx] = W_hh1[(size_t)j*512 + k];
    wih1_s[idx] = W_ih1[(size_t)j*512 + k];
  }
  for (int idx = tid; idx < 2*512; idx += 256){
    int dd = idx >> 9, k = idx & 511;
    wdec_s[idx] = W_att_dec[(size_t)k*512 + d0 + dd];
  }
  for (int idx = tid; idx < 4*1000; idx += 256){
    int gp = idx & 3, tg = idx >> 2;
    int b = tg / 250, t = tg - b*250;
    const float2 v = *(const float2*)(hsW0 + (size_t)tg*G_ + gp*512 + d0);
    hsw_s[(b*8 + gp*2 + 0)*256 + t] = v.x;
    hsw_s[(b*8 + gp*2 + 1)*256 + t] = v.y;
  }
  for (int idx = tid; idx < 4*8*6; idx += 256){   // zero t-pad 250..255
    int t = 250 + (idx % 6), bg = idx / 6;
    hsw_s[bg*256 + t] = 0.f;
  }
  for (int idx = tid; idx < 480*4; idx += 256){
    int gp = idx & 3, r = idx >> 2;
    const float2 v = *(const float2*)(pre0 + (size_t)r*G_ + gp*512 + d0);
    pre0_s[r*8 + gp*2 + 0] = v.x;
    pre0_s[r*8 + gp*2 + 1] = v.y;
  }
  for (int idx = tid; idx < 4*512; idx += 256){
    int r = bk*4 + (idx >> 9);
    pre_s[idx] = (r < B_*T_) ? pre_enc[(size_t)r*512 + (idx & 511)] : 0.f;
  }
  for (int idx = tid; idx < 512; idx += 256) gvec_s[idx] = gvec[idx];
  for (int idx = tid; idx < 2048; idx += 256) zs0[idx] = 0.f;   // z0(-1) = 0
  if (tid < 4) hlens_s[tid] = hlens[tid];
  if (tid < 32){ pA0[tid] = 0.f; }   // z0(-1)@Whh0 = 0
  if (tid < 8){
    int j = ((tid >> 1))*512 + d0 + (tid & 1);
    bias0_s[tid] = b_ih0[j] + b_hh0[j];
    bias1_s[tid] = b_ih1[j] + b_hh1[j];
    c0_s[tid] = 0.f; c1_s[tid] = 0.f;
    int b = tid >> 1, d = d0 + (tid & 1);
    atomStoreF(&z1[b*512 + d], 0.f);
    atomStoreF(&q [b*512 + d], 0.f);
  }
  int gen = 0;
  gbar(flags, rel, ++gen);

  for (int u = 0; u < U_; ++u){
    // ---- Phase A: issue q (4) then z1 (8); wait q only; e-compute hides z1 ----
    float vq0,vq1,vq2,vq3;
    float vz0,vz1,vz2,vz3,vz4,vz5,vz6,vz7;
    {
      const float* qa = &q[b_lo*512 + tid*2];
      const float* qb = &q[b_hi*512 + tid*2];
      asm volatile(
        "global_load_dword %0, %12, off sc0 sc1\n\t"
        "global_load_dword %1, %13, off sc0 sc1\n\t"
        "global_load_dword %2, %14, off sc0 sc1\n\t"
        "global_load_dword %3, %15, off sc0 sc1\n\t"
        "global_load_dword %4, %16, off sc0 sc1\n\t"
        "global_load_dword %5, %17, off sc0 sc1\n\t"
        "global_load_dword %6, %18, off sc0 sc1\n\t"
        "global_load_dword %7, %19, off sc0 sc1\n\t"
        "global_load_dword %8, %20, off sc0 sc1\n\t"
        "global_load_dword %9, %21, off sc0 sc1\n\t"
        "global_load_dword %10, %22, off sc0 sc1\n\t"
        "global_load_dword %11, %23, off sc0 sc1\n\t"
        "s_waitcnt vmcnt(8)"
        : "=&v"(vq0),"=&v"(vq1),"=&v"(vq2),"=&v"(vq3),
          "=&v"(vz0),"=&v"(vz1),"=&v"(vz2),"=&v"(vz3),
          "=&v"(vz4),"=&v"(vz5),"=&v"(vz6),"=&v"(vz7)
        : "v"(qa), "v"(qa+1), "v"(qb), "v"(qb+1),
          "v"(&z1[tid]), "v"(&z1[tid+256]), "v"(&z1[tid+512]), "v"(&z1[tid+768]),
          "v"(&z1[tid+1024]), "v"(&z1[tid+1280]), "v"(&z1[tid+1536]), "v"(&z1[tid+1792])
        : "memory");
      qs[b_lo*512 + tid*2]     = vq0;
      qs[b_lo*512 + tid*2 + 1] = vq1;
      qs[b_hi*512 + tid*2]     = vq2;
      qs[b_hi*512 + tid*2 + 1] = vq3;
    }
    __syncthreads();
    {
      int r = bk*4 + wv;
      if (r < B_*T_){
        int b = r / 250, t = r - b*250;
        float s = 0.f;
#pragma unroll
        for (int i=0;i<8;i++){
          int k = i*64 + lane;
          float x = pre_s[wv*512+k] + qs[b*512+k];
          s += tanh_fast(x) * gvec_s[k];
        }
#pragma unroll
        for (int off=32; off; off>>=1) s += __shfl_xor(s, off);
        if (lane == 0) atomStoreF(&e[r], (t < hlens_s[b]) ? s : -1e30f);
      }
    }
    // drain z1 loads, land into LDS
    asm volatile("s_waitcnt vmcnt(0)"
      : "+v"(vz0),"+v"(vz1),"+v"(vz2),"+v"(vz3),
        "+v"(vz4),"+v"(vz5),"+v"(vz6),"+v"(vz7) :: "memory");
    __builtin_amdgcn_sched_barrier(0);
    zs1[tid]      = vz0; zs1[tid+256]  = vz1; zs1[tid+512]  = vz2; zs1[tid+768]  = vz3;
    zs1[tid+1024] = vz4; zs1[tid+1280] = vz5; zs1[tid+1536] = vz6; zs1[tid+1792] = vz7;
    gbar_arrive(flags, ++gen);
    {   // overlap: pA1 = z1(u-1) @ Whh1 (consumed in phase C)
      int gd0 = wv*2, gd1 = wv*2 + 1;
      float a10[4]={}, a11[4]={};
#pragma unroll
      for (int i = 0; i < 8; ++i){
        int k = i*64 + lane;
        float w10 = whh1_s[gd0*512+k], w11 = whh1_s[gd1*512+k];
#pragma unroll
        for (int b=0;b<4;b++){
          float zv1 = zs1[b*512+k];
          a10[b] += w10*zv1; a11[b] += w11*zv1;
        }
      }
#pragma unroll
      for (int b=0;b<4;b++){
#pragma unroll
        for (int off=32; off; off>>=1){
          a10[b] += __shfl_xor(a10[b],off); a11[b] += __shfl_xor(a11[b],off);
        }
      }
      if (lane == 0){
#pragma unroll
        for (int b=0;b<4;b++){ pA1[b*8+gd0] = a10[b]; pA1[b*8+gd1] = a11[b]; }
      }
    }
    gbar_wait(flags, rel, gen);
    // ---- Phase B: softmax + gates0 -> z0' ----
    {
      int b = wv;
      const float* eb = e + b*250;
      float vals[4], w_reg[4];
      int t3 = 192 + lane;
      mall_load4f(eb + lane, eb + 64 + lane, eb + 128 + lane,
                  eb + (t3 < 250 ? t3 : 249),
                  vals[0], vals[1], vals[2], vals[3]);
      if (t3 >= 250) vals[3] = -1e30f;
      float vmax = fmaxf(fmaxf(vals[0],vals[1]), fmaxf(vals[2],vals[3]));
#pragma unroll
      for (int off=32; off; off>>=1) vmax = fmaxf(vmax, __shfl_xor(vmax, off));
      float ssum = 0.f;
#pragma unroll
      for (int i=0;i<4;i++){
        int t = i*64 + lane;
        w_reg[i] = (t < 250) ? __expf(vals[i] - vmax) : 0.f;
        ssum += w_reg[i];
      }
#pragma unroll
      for (int off=32; off; off>>=1) ssum += __shfl_xor(ssum, off);
      float inv = 1.f / ssum;
#pragma unroll
      for (int i=0;i<4;i++) w_reg[i] *= inv;

      float ag[8] = {};
#pragma unroll
      for (int i=0;i<4;i++){
        int t = i*64 + lane;
#pragma unroll
        for (int gd=0; gd<8; gd++)
          ag[gd] += w_reg[i] * hsw_s[(b*8+gd)*256 + t];
      }
#pragma unroll
      for (int gd=0; gd<8; gd++){
#pragma unroll
        for (int off=32; off; off>>=1) ag[gd] += __shfl_xor(ag[gd], off);
      }
      if (lane == 0){
#pragma unroll
        for (int gd=0; gd<8; gd++)
          gB[b*8+gd] = ag[gd] + pA0[b*8+gd] + pre0_s[(b*U_+u)*8 + gd] + bias0_s[gd];
      }
    }
    __syncthreads();
    if (tid < 8){
      int b = tid >> 1, dd = tid & 1;
      float ig = sigmoid_fast(gB[b*8 + 0 + dd]);
      float fg = sigmoid_fast(gB[b*8 + 2 + dd]);
      float gg = tanh_fast  (gB[b*8 + 4 + dd]);
      float og = sigmoid_fast(gB[b*8 + 6 + dd]);
      float cn = fg * c0_s[tid] + ig * gg;
      c0_s[tid] = cn;
      atomStoreF(&z0[b*512 + d0 + dd], og * tanh_fast(cn));
    }
    gbar(flags, rel, ++gen);   // nothing independent to overlap
    // ---- Phase C: load z0(u); gates1 + q; arrive; overlap pA0(u+1); wait
    {
      float vza[8];
#pragma unroll
      for (int i=0;i<8;i++)
        asm volatile("global_load_dword %0, %1, off sc0 sc1"
                     : "=&v"(vza[i]) : "v"(&z0[tid + 256*i]));
      asm volatile("s_waitcnt vmcnt(0)" ::: "memory");
#pragma unroll
      for (int i=0;i<8;i++) zs0[tid + 256*i] = vza[i];   // z0(u), reused next A/B
    }
    __syncthreads();
    {
      int gd0 = wv*2, gd1 = wv*2 + 1;
      float a0[4]={}, a1[4]={};
#pragma unroll
      for (int i=0;i<8;i++){
        int k = i*64 + lane;
        float w0 = wih1_s[gd0*512+k], w1 = wih1_s[gd1*512+k];
#pragma unroll
        for (int b=0;b<4;b++){
          float zv = zs0[b*512+k];
          a0[b] += w0*zv; a1[b] += w1*zv;
        }
      }
#pragma unroll
      for (int b=0;b<4;b++){
#pragma unroll
        for (int off=32; off; off>>=1){
          a0[b] += __shfl_xor(a0[b],off); a1[b] += __shfl_xor(a1[b],off);
        }
      }
      if (lane == 0){
#pragma unroll
        for (int b=0;b<4;b++){
          gC[b*8+gd0] = a0[b] + pA1[b*8+gd0] + bias1_s[gd0];
          gC[b*8+gd1] = a1[b] + pA1[b*8+gd1] + bias1_s[gd1];
        }
      }
      if (wv < 2){
        float qa[4] = {};
#pragma unroll
        for (int i=0;i<8;i++){
          int k = i*64 + lane;
          float wq = wdec_s[wv*512+k];
#pragma unroll
          for (int b=0;b<4;b++) qa[b] += wq * zs0[b*512+k];
        }
#pragma unroll
        for (int b=0;b<4;b++){
#pragma unroll
          for (int off=32; off; off>>=1) qa[b] += __shfl_xor(qa[b],off);
        }
        if (lane == 0){
#pragma unroll
          for (int b=0;b<4;b++) atomStoreF(&q[b*512 + d0 + wv], qa[b]);
        }
      }
    }
    __syncthreads();
    if (tid < 8){
      int b = tid >> 1, dd = tid & 1;
      float ig = sigmoid_fast(gC[b*8 + 0 + dd]);
      float fg = sigmoid_fast(gC[b*8 + 2 + dd]);
      float gg = tanh_fast  (gC[b*8 + 4 + dd]);
      float og = sigmoid_fast(gC[b*8 + 6 + dd]);
      float cn = fg * c1_s[tid] + ig * gg;
      c1_s[tid] = cn;
      float hn = og * tanh_fast(cn);
      atomStoreF(&z1[b*512 + d0 + dd], hn);
      h_dec[((size_t)(b*U_ + u))*512 + d0 + dd] = hn;
    }
    gbar_arrive(flags, ++gen);
    {   // overlap: pA0(u+1) = z0(u) @ Whh0 (consumed in next phase B)
      int gd0 = wv*2, gd1 = wv*2 + 1;
      float a00[4]={}, a01[4]={};
#pragma unroll
      for (int i = 0; i < 8; ++i){
        int k = i*64 + lane;
        float w00 = whh0_s[gd0*512+k], w01 = whh0_s[gd1*512+k];
#pragma unroll
        for (int b=0;b<4;b++){
          float zv0 = zs0[b*512+k];
          a00[b] += w00*zv0; a01[b] += w01*zv0;
        }
      }
#pragma unroll
      for (int b=0;b<4;b++){
#pragma unroll
        for (int off=32; off; off>>=1){
          a00[b] += __shfl_xor(a00[b],off); a01[b] += __shfl_xor(a01[b],off);
        }
      }
      if (lane == 0){
#pragma unroll
        for (int b=0;b<4;b++){ pA0[b*8+gd0] = a00[b]; pA0[b*8+gd1] = a01[b]; }
      }
    }
    gbar_wait(flags, rel, gen);
  }
}

// ---------- bf16 MFMA joint path ----------
__global__ __launch_bounds__(256) void pack_k(
    const float* __restrict__ henc, const float* __restrict__ hdec,
    unsigned short* __restrict__ P,
    const float* __restrict__ Wlin, unsigned short* __restrict__ Wb)
{
  const int NP8 = B_*T_*U_*512/8;
  int i = blockIdx.x*256 + threadIdx.x;
  if (i < NP8){
    int e = i*8;
    int k = e & 511;
    int r = e >> 9;
    int u = r % U_;
    int bt = r / U_;
    int b = bt / T_;
    const float* hp = henc + (size_t)bt*512 + k;
    const float* dp = hdec + (size_t)(b*U_ + u)*512 + k;
    unsigned int w[4];
#pragma unroll
    for (int j=0;j<4;j++){
      unsigned short lo = f2bf(tanh_fast(hp[2*j]   + dp[2*j]));
      unsigned short hi = f2bf(tanh_fast(hp[2*j+1] + dp[2*j+1]));
      w[j] = (unsigned int)lo | ((unsigned int)hi << 16);
    }
    *(ui4*)(P + e) = ui4{w[0], w[1], w[2], w[3]};
  } else {
    int j8 = i - NP8;
    if (j8 < O_*512/8){
      int e = j8*8;
      unsigned int w[4];
#pragma unroll
      for (int j=0;j<4;j++){
        unsigned short lo = f2bf(Wlin[e+2*j]);
        unsigned short hi = f2bf(Wlin[e+2*j+1]);
        w[j] = (unsigned int)lo | ((unsigned int)hi << 16);
      }
      *(ui4*)(Wb + e) = ui4{w[0], w[1], w[2], w[3]};
    }
  }
}

// joint GEMM, 1-D grid (bt-major for XCD L2 sharing), coalesced LDS-repack epilogue
__global__ __launch_bounds__(256) void joint_mfma_k(
    const unsigned short* __restrict__ P,
    const unsigned short* __restrict__ Wb,
    const float* __restrict__ bout,
    float* __restrict__ out)
{
  __shared__ __align__(16) char smraw[32768];
  unsigned short* As = (unsigned short*)smraw;            // 16 KB
  unsigned short* Bs = (unsigned short*)(smraw + 16384);  // 16 KB
  float* outb = (float*)smraw;                            // 32x132 f32, reused post-loop
  int tid = threadIdx.x;
  int lane = tid & 63;
  int w = tid >> 6, wr = w >> 1, wc = w & 1;
  int id = blockIdx.x;
  int bt = id % 1000;        // 1000%8==0 -> all 8 o-tiles of bt on same XCD
  int ot = id / 1000;
  int o0 = ot * 128;
  const char* Pbase = (const char*)(P + (size_t)bt*U_*512);
  const char* Wbase = (const char*)(Wb + (size_t)o0*512);

  f32x4 acc[4][4] = {};

  for (int k0 = 0; k0 < 512; k0 += 64){
    __syncthreads();
#pragma unroll
    for (int j=0;j<4;j++){
      int pos = (j*256 + tid)*16;
      int row = pos >> 7;
      int inrow = pos & 127;
      int srcin = inrow ^ ((row & 7) << 4);
      int arow = row < U_ ? row : (U_-1);
      __builtin_amdgcn_global_load_lds(
        (const __attribute__((address_space(1))) void*)(Pbase + (size_t)arow*1024 + k0*2 + srcin),
        (__attribute__((address_space(3))) void*)((char*)As + pos), 16, 0, 0);
      __builtin_amdgcn_global_load_lds(
        (const __attribute__((address_space(1))) void*)(Wbase + (size_t)row*1024 + k0*2 + srcin),
        (__attribute__((address_space(3))) void*)((char*)Bs + pos), 16, 0, 0);
    }
    __syncthreads();
#pragma unroll
    for (int kk=0; kk<2; kk++){
      bf16x8 a[4], bb[4];
#pragma unroll
      for (int m=0;m<4;m++){
        int row = wr*64 + m*16 + (lane & 15);
        int inrow = (kk*64 + (lane >> 4)*16) ^ ((row & 7) << 4);
        a[m] = *(const bf16x8*)((const char*)As + row*128 + inrow);
      }
#pragma unroll
      for (int n=0;n<4;n++){
        int row = wc*64 + n*16 + (lane & 15);
        int inrow = (kk*64 + (lane >> 4)*16) ^ ((row & 7) << 4);
        bb[n] = *(const bf16x8*)((const char*)Bs + row*128 + inrow);
      }
#pragma unroll
      for (int m=0;m<4;m++)
#pragma unroll
        for (int n=0;n<4;n++)
          acc[m][n] = __builtin_amdgcn_mfma_f32_16x16x32_bf16(a[m], bb[n], acc[m][n], 0, 0, 0);
    }
  }
  // epilogue: per m, stage 32(u) x 128(o) f32 tile in LDS, then coalesced stores
  float bv[4];
#pragma unroll
  for (int n=0;n<4;n++) bv[n] = bout[o0 + wc*64 + n*16 + (lane & 15)];
#pragma unroll
  for (int m=0;m<4;m++){
    __syncthreads();
#pragma unroll
    for (int n=0;n<4;n++){
      int col = wc*64 + n*16 + (lane & 15);
      int r0 = wr*16 + ((lane >> 4) << 2);
#pragma unroll
      for (int r=0;r<4;r++)
        outb[(r0+r)*132 + col] = acc[m][n][r] + bv[n];
    }
    __syncthreads();
    int row = tid >> 3;          // 0..31
    int c0  = (tid & 7) * 16;    // 0..112
    int u = (row < 16) ? (m*16 + row) : (64 + m*16 + (row - 16));
    if (u < U_){
      float* op = out + ((size_t)bt*U_ + u)*O_ + o0 + c0;
      const float* sp = &outb[row*132 + c0];
#pragma unroll
      for (int i=0;i<4;i++) *(f32x4*)(op + 4*i) = *(const f32x4*)(sp + 4*i);
    }
  }
}

extern "C" void kernel_launch(void* const* d_in, const int* in_sizes, int n_in,
                              void* d_out, int out_size, void* d_ws, size_t ws_size,
                              hipStream_t stream) {
  const float* hs       = (const float*)d_in[0];
  const int*   ys       = (const int*)  d_in[1];
  const int*   hlens    = (const int*)  d_in[2];
  const float* embed    = (const float*)d_in[3];
  const float* W_ih0    = (const float*)d_in[4];
  const float* b_ih0    = (const float*)d_in[5];
  const float* W_hh0    = (const float*)d_in[6];
  const float* b_hh0    = (const float*)d_in[7];
  const float* W_ih1    = (const float*)d_in[8];
  const float* b_ih1    = (const float*)d_in[9];
  const float* W_hh1    = (const float*)d_in[10];
  const float* b_hh1    = (const float*)d_in[11];
  const float* W_att_enc= (const float*)d_in[12];
  const float* b_att_enc= (const float*)d_in[13];
  const float* W_att_dec= (const float*)d_in[14];
  const float* gvec     = (const float*)d_in[15];
  const float* W_lin_enc= (const float*)d_in[16];
  const float* b_lin_enc= (const float*)d_in[17];
  const float* W_lin_dec= (const float*)d_in[18];
  const float* W_lin_out= (const float*)d_in[19];
  const float* b_lin_out= (const float*)d_in[20];
  float* out = (float*)d_out;

  float* w = (float*)d_ws;
  // ws layout (float offsets)
  float* z0      = w;              // 2048
  float* z1      = w + 2048;       // 2048
  float* q       = w + 4096;       // 2048
  float* e       = w + 6144;       // 1024
  int*   flags   = (int*)(w + 7168); // 256*16+16 ints (padded arrivals + rel)
  int*   rel     = flags + NBLK*16;
  float* eys     = w + 11776;      // 245760
  float* pre_enc = w + 257536;     // 512000
  float* pre0    = w + 769536;     // 983040
  float* henc    = w + 1752576;    // 512000
  float* h_dec   = w + 2264576;    // 245760
  float* hdec_p  = w + 2510336;    // 245760
  float* hsW0    = w + 2756096;    // 2048000 -> 4804096
  unsigned short* Pbf = (unsigned short*)(w + 4804096);            // 61,440,000 bf16
  unsigned short* Wbf = (unsigned short*)(w + 4804096 + 30720000); // 524,288 bf16

  gather_embed_k<<<(B_*U_*D_ + 255)/256, 256, 0, stream>>>(ys, embed, eys, flags);
  // fused: pre_enc | henc | pre0 | hsW0 (exactly 256 blocks)
  pre_gemms_k<<<256, 256, 0, stream>>>(hs, eys, W_att_enc, b_att_enc,
                                       W_lin_enc, b_lin_enc, W_ih0,
                                       pre_enc, henc, pre0, hsW0);

  // LDS-resident scan (cooperative launch for co-residency; own barrier inside)
  {
    void* args[] = {
      (void*)&z0, (void*)&z1, (void*)&q, (void*)&e, (void*)&flags, (void*)&rel,
      (void*)&pre_enc, (void*)&pre0, (void*)&hsW0,
      (void*)&W_hh0, (void*)&W_ih1, (void*)&W_hh1, (void*)&W_att_dec,
      (void*)&gvec, (void*)&hlens,
      (void*)&b_ih0, (void*)&b_hh0, (void*)&b_ih1, (void*)&b_hh1,
      (void*)&h_dec
    };
    hipLaunchCooperativeKernel((const void*)scan_k, dim3(NBLK), dim3(256),
                               args, 0, stream);
  }

  // hdec = h_dec @ W_lin_dec^T
  gemm64_nt_k<<<dim3(8, 8), 256, 0, stream>>>(h_dec, 512, W_lin_dec, 512, nullptr,
                                              hdec_p, 512, B_*U_, 512, 512);
  // P = tanh(henc+hdec) bf16; Wb = bf16(W_lin_out)
  {
    const int NP8 = B_*T_*U_*512/8;
    const int NW8 = O_*512/8;
    pack_k<<<(NP8 + NW8 + 255)/256, 256, 0, stream>>>(henc, hdec_p, Pbf,
                                                      W_lin_out, Wbf);
  }
  joint_mfma_k<<<8000, 256, 0, stream>>>(Pbf, Wbf, b_lin_out, out);
}

// Round 12
// 1900.151 us; speedup vs baseline: 1.0413x; 1.0413x over previous
//
#include <hip/hip_runtime.h>

#define B_ 4
#define T_ 250
#define U_ 120
#define D_ 512
#define G_ 2048   // 4*D (gates)
#define O_ 1024   // odim
#define NBLK 256

typedef __attribute__((ext_vector_type(8))) short bf16x8;
typedef __attribute__((ext_vector_type(4))) float f32x4;
typedef __attribute__((ext_vector_type(4))) unsigned int ui4;

__device__ __forceinline__ float tanh_fast(float x){
  float e = __expf(2.f*x);
  return 1.f - 2.f/(e + 1.f);
}
__device__ __forceinline__ float sigmoid_fast(float x){
  return 1.f/(1.f + __expf(-x));
}
__device__ __forceinline__ unsigned short f2bf(float x){
  unsigned int u = __float_as_uint(x);
  unsigned int r = (u + 0x7FFFu + ((u >> 16) & 1u)) >> 16;
  return (unsigned short)r;
}

// MALL-coherent single-value ops
__device__ __forceinline__ void atomStoreF(float* p, float v){
  __hip_atomic_store(p, v, __ATOMIC_RELAXED, __HIP_MEMORY_SCOPE_AGENT);
}
__device__ __forceinline__ void mall_load4f(const float* p0, const float* p1,
    const float* p2, const float* p3, float& v0, float& v1, float& v2, float& v3){
  asm volatile(
    "global_load_dword %0, %4, off sc0 sc1\n\t"
    "global_load_dword %1, %5, off sc0 sc1\n\t"
    "global_load_dword %2, %6, off sc0 sc1\n\t"
    "global_load_dword %3, %7, off sc0 sc1\n\t"
    "s_waitcnt vmcnt(0)"
    : "=&v"(v0), "=&v"(v1), "=&v"(v2), "=&v"(v3)
    : "v"(p0), "v"(p1), "v"(p2), "v"(p3)
    : "memory");
}

// barrier v4: split arrive/wait so independent compute hides the round trips.
__device__ __forceinline__ void gbar_arrive(int* flags, int gen){
  __syncthreads();
  if (threadIdx.x == 0){
    asm volatile("s_waitcnt vmcnt(0)" ::: "memory");
    __hip_atomic_store(&flags[blockIdx.x*16], gen, __ATOMIC_RELAXED,
                       __HIP_MEMORY_SCOPE_AGENT);
  }
}
__device__ __forceinline__ void gbar_wait(int* flags, int* rel, int gen){
  if (blockIdx.x == 0){
    if (threadIdx.x < 64){
      int l = threadIdx.x;
      const int* p0 = flags + (l*4+0)*16;
      const int* p1 = flags + (l*4+1)*16;
      const int* p2 = flags + (l*4+2)*16;
      const int* p3 = flags + (l*4+3)*16;
      long c = 0;
      while (true){
        int f0,f1,f2,f3;
        asm volatile(
          "global_load_dword %0, %4, off sc0 sc1\n\t"
          "global_load_dword %1, %5, off sc0 sc1\n\t"
          "global_load_dword %2, %6, off sc0 sc1\n\t"
          "global_load_dword %3, %7, off sc0 sc1\n\t"
          "s_waitcnt vmcnt(0)"
          : "=&v"(f0),"=&v"(f1),"=&v"(f2),"=&v"(f3)
          : "v"(p0), "v"(p1), "v"(p2), "v"(p3)
          : "memory");
        int m0 = f0 < f1 ? f0 : f1;
        int m1 = f2 < f3 ? f2 : f3;
        int mm = m0 < m1 ? m0 : m1;
        if (__all(mm >= gen)) break;
        if (++c > (1L<<22)) break;   // anti-hang valve
      }
      if (threadIdx.x == 0)
        __hip_atomic_store(rel, gen, __ATOMIC_RELAXED,
                           __HIP_MEMORY_SCOPE_AGENT);
    }
  } else {
    if (threadIdx.x == 0){
      long c = 0;
      while (__hip_atomic_load(rel, __ATOMIC_RELAXED,
                               __HIP_MEMORY_SCOPE_AGENT) < gen){
        if (++c > (1L<<22)) break;
      }
    }
  }
  __syncthreads();
}
__device__ __forceinline__ void gbar(int* flags, int* rel, int gen){
  gbar_arrive(flags, gen);
  gbar_wait(flags, rel, gen);
}

// gather + flag-init fused
__global__ void gather_embed_k(const int* __restrict__ ys, const float* __restrict__ embed,
                               float* __restrict__ eys, int* __restrict__ flags){
  int i = blockIdx.x*256 + threadIdx.x;
  if (i < NBLK*16 + 16)
    __hip_atomic_store(&flags[i], 0, __ATOMIC_RELAXED, __HIP_MEMORY_SCOPE_AGENT);
  if (i < B_*U_*D_){
    int r = i >> 9, k = i & 511;
    eys[i] = embed[ys[r]*D_ + k];
  }
}

// ---------- 64x64 GEMM bodies ----------
__device__ __forceinline__ void gemm64_nt_body(float* smem,
  const float* __restrict__ A, int lda, const float* __restrict__ B, int ldb,
  const float* __restrict__ bias, float* __restrict__ C, int ldc,
  int M, int N, int K, int bx, int by)
{
  float (*As)[65] = (float(*)[65])smem;
  float (*Bs)[65] = (float(*)[65])(smem + 16*65);
  int tid = threadIdx.x;
  int m0 = by*64, n0 = bx*64;
  int tx = tid & 15, ty = tid >> 4;
  float acc[4][4] = {};
  for (int k0 = 0; k0 < K; k0 += 16){
#pragma unroll
    for (int i=0;i<4;i++){
      int e = tid + 256*i;
      int mm = e >> 4, kk = e & 15;
      int mg = m0 + mm;
      As[kk][mm] = (mg < M) ? A[(size_t)mg*lda + k0 + kk] : 0.f;
      int ng = n0 + mm;
      Bs[kk][mm] = (ng < N) ? B[(size_t)ng*ldb + k0 + kk] : 0.f;
    }
    __syncthreads();
#pragma unroll
    for (int kk=0;kk<16;kk++){
      float av[4], bv[4];
#pragma unroll
      for (int i=0;i<4;i++) av[i] = As[kk][ty*4+i];
#pragma unroll
      for (int j=0;j<4;j++) bv[j] = Bs[kk][tx*4+j];
#pragma unroll
      for (int i=0;i<4;i++)
#pragma unroll
        for (int j=0;j<4;j++) acc[i][j] += av[i]*bv[j];
    }
    __syncthreads();
  }
#pragma unroll
  for (int i=0;i<4;i++){
    int m = m0 + ty*4 + i;
    if (m < M){
#pragma unroll
      for (int j=0;j<4;j++){
        int n = n0 + tx*4 + j;
        if (n < N) C[(size_t)m*ldc + n] = acc[i][j] + (bias ? bias[n] : 0.f);
      }
    }
  }
}

__device__ __forceinline__ void gemm64_nn_body(float* smem,
  const float* __restrict__ A, int lda, const float* __restrict__ B, int ldb,
  const float* __restrict__ bias, float* __restrict__ C, int ldc,
  int M, int N, int K, int bx, int by)
{
  float (*As)[65] = (float(*)[65])smem;
  float (*Bs)[65] = (float(*)[65])(smem + 16*65);
  int tid = threadIdx.x;
  int m0 = by*64, n0 = bx*64;
  int tx = tid & 15, ty = tid >> 4;
  float acc[4][4] = {};
  for (int k0 = 0; k0 < K; k0 += 16){
#pragma unroll
    for (int i=0;i<4;i++){
      int e = tid + 256*i;
      int mm = e >> 4, kk = e & 15;
      int mg = m0 + mm;
      As[kk][mm] = (mg < M) ? A[(size_t)mg*lda + k0 + kk] : 0.f;
      int nn = e & 63, kk2 = e >> 6;
      int ng = n0 + nn;
      Bs[kk2][nn] = (ng < N) ? B[(size_t)(k0+kk2)*ldb + ng] : 0.f;
    }
    __syncthreads();
#pragma unroll
    for (int kk=0;kk<16;kk++){
      float av[4], bv[4];
#pragma unroll
      for (int i=0;i<4;i++) av[i] = As[kk][ty*4+i];
#pragma unroll
      for (int j=0;j<4;j++) bv[j] = Bs[kk][tx*4+j];
#pragma unroll
      for (int i=0;i<4;i++)
#pragma unroll
        for (int j=0;j<4;j++) acc[i][j] += av[i]*bv[j];
    }
    __syncthreads();
  }
#pragma unroll
  for (int i=0;i<4;i++){
    int m = m0 + ty*4 + i;
    if (m < M){
#pragma unroll
      for (int j=0;j<4;j++){
        int n = n0 + tx*4 + j;
        if (n < N) C[(size_t)m*ldc + n] = acc[i][j] + (bias ? bias[n] : 0.f);
      }
    }
  }
}

// fused precompute (round-10 proven): 1024 blocks of 64^2 tiles
__global__ __launch_bounds__(256) void pre_gemms_k(
  const float* __restrict__ hs, const float* __restrict__ eys,
  const float* __restrict__ W_att_enc, const float* __restrict__ b_att_enc,
  const float* __restrict__ W_lin_enc, const float* __restrict__ b_lin_enc,
  const float* __restrict__ W_ih0,
  float* __restrict__ pre_enc, float* __restrict__ henc,
  float* __restrict__ pre0, float* __restrict__ hsW0)
{
  __shared__ float smem[2*16*65];
  int id = blockIdx.x;
  if (id < 128){
    gemm64_nn_body(smem, hs,512, W_att_enc,512, b_att_enc, pre_enc,512,
                   B_*T_,512,512, id & 7, id >> 3);
  } else if (id < 256){
    id -= 128;
    gemm64_nt_body(smem, hs,512, W_lin_enc,512, b_lin_enc, henc,512,
                   B_*T_,512,512, id & 7, id >> 3);
  } else if (id < 512){
    id -= 256;
    gemm64_nt_body(smem, eys,512, W_ih0,1024, nullptr, pre0,2048,
                   B_*U_,2048,512, id & 31, id >> 5);
  } else {
    id -= 512;
    gemm64_nt_body(smem, hs,512, W_ih0+512,1024, nullptr, hsW0,2048,
                   B_*T_,2048,512, id & 31, id >> 5);
  }
}

// standalone nt for hdec (post-scan)
__global__ __launch_bounds__(256) void gemm64_nt_k(
  const float* __restrict__ A, int lda, const float* __restrict__ B, int ldb,
  const float* __restrict__ bias, float* __restrict__ C, int ldc,
  int M, int N, int K)
{
  __shared__ float smem[2*16*65];
  gemm64_nt_body(smem, A,lda,B,ldb,bias,C,ldc,M,N,K, blockIdx.x, blockIdx.y);
}

// ---------- LDS-resident scan (round-10 exact), barrier v4 with overlap ----------
__global__ __launch_bounds__(256) void scan_k(
    float* __restrict__ z0, float* __restrict__ z1,
    float* __restrict__ q,  float* __restrict__ e,
    int* __restrict__ flags, int* __restrict__ rel,
    const float* __restrict__ pre_enc, const float* __restrict__ pre0,
    const float* __restrict__ hsW0,
    const float* __restrict__ W_hh0, const float* __restrict__ W_ih1,
    const float* __restrict__ W_hh1, const float* __restrict__ W_att_dec,
    const float* __restrict__ gvec, const int* __restrict__ hlens,
    const float* __restrict__ b_ih0, const float* __restrict__ b_hh0,
    const float* __restrict__ b_ih1, const float* __restrict__ b_hh1,
    float* __restrict__ h_dec)
{
  int bk = blockIdx.x, tid = threadIdx.x;
  int lane = tid & 63, wv = tid >> 6;
  int d0 = bk * 2;

  __shared__ float whh0_s[8*512];   // [gd][k]
  __shared__ float whh1_s[8*512];
  __shared__ float wih1_s[8*512];
  __shared__ float wdec_s[2*512];   // [delta][k]
  __shared__ float hsw_s[4*8*256];  // [b][gd][t(pad 256)]
  __shared__ float pre0_s[480*8];   // [(b*120+u)][gd]
  __shared__ float pre_s[4*512];    // e-rows
  __shared__ float gvec_s[512];
  __shared__ float zs0[2048], zs1[2048], qs[2048];
  __shared__ float pA0[32], pA1[32], gB[32], gC[32];
  __shared__ float bias0_s[8], bias1_s[8], c0_s[8], c1_s[8];
  __shared__ int hlens_s[4];

  // ---- one-time LDS load ----
  for (int idx = tid; idx < 8*512; idx += 256){
    int gd = idx >> 9, k = idx & 511;
    int j = (gd >> 1)*512 + d0 + (gd & 1);
    whh0_s[idx] = W_hh0[(size_t)j*512 + k];
    whh1_s[idx] = W_hh1[(size_t)j*512 + k];
    wih1_s[idx] = W_ih1[(size_t)j*512 + k];
  }
  for (int idx = tid; idx < 2*512; idx += 256){
    int dd = idx >> 9, k = idx & 511;
    wdec_s[idx] = W_att_dec[(size_t)k*512 + d0 + dd];
  }
  for (int idx = tid; idx < 4*1000; idx += 256){
    int gp = idx & 3, tg = idx >> 2;
    int b = tg / 250, t = tg - b*250;
    const float2 v = *(const float2*)(hsW0 + (size_t)tg*G_ + gp*512 + d0);
    hsw_s[(b*8 + gp*2 + 0)*256 + t] = v.x;
    hsw_s[(b*8 + gp*2 + 1)*256 + t] = v.y;
  }
  for (int idx = tid; idx < 4*8*6; idx += 256){   // zero t-pad 250..255
    int t = 250 + (idx % 6), bg = idx / 6;
    hsw_s[bg*256 + t] = 0.f;
  }
  for (int idx = tid; idx < 480*4; idx += 256){
    int gp = idx & 3, r = idx >> 2;
    const float2 v = *(const float2*)(pre0 + (size_t)r*G_ + gp*512 + d0);
    pre0_s[r*8 + gp*2 + 0] = v.x;
    pre0_s[r*8 + gp*2 + 1] = v.y;
  }
  for (int idx = tid; idx < 4*512; idx += 256){
    int r = bk*4 + (idx >> 9);
    pre_s[idx] = (r < B_*T_) ? pre_enc[(size_t)r*512 + (idx & 511)] : 0.f;
  }
  for (int idx = tid; idx < 512; idx += 256) gvec_s[idx] = gvec[idx];
  for (int idx = tid; idx < 2048; idx += 256) zs0[idx] = 0.f;   // z0(-1) = 0
  if (tid < 4) hlens_s[tid] = hlens[tid];
  if (tid < 32){ pA0[tid] = 0.f; }   // z0(-1)@Whh0 = 0
  if (tid < 8){
    int j = ((tid >> 1))*512 + d0 + (tid & 1);
    bias0_s[tid] = b_ih0[j] + b_hh0[j];
    bias1_s[tid] = b_ih1[j] + b_hh1[j];
    c0_s[tid] = 0.f; c1_s[tid] = 0.f;
    int b = tid >> 1, d = d0 + (tid & 1);
    atomStoreF(&z1[b*512 + d], 0.f);
    atomStoreF(&q [b*512 + d], 0.f);
  }
  int gen = 0;
  gbar(flags, rel, ++gen);

  for (int u = 0; u < U_; ++u){
    // ---- Phase A: load z1(u-1),q(u-1); compute e(u); arrive; overlap pA1; wait
    {
      float vz[8], vq[8];
#pragma unroll
      for (int i=0;i<8;i++)
        asm volatile("global_load_dword %0, %1, off sc0 sc1"
                     : "=&v"(vz[i]) : "v"(&z1[tid + 256*i]));
#pragma unroll
      for (int i=0;i<8;i++)
        asm volatile("global_load_dword %0, %1, off sc0 sc1"
                     : "=&v"(vq[i]) : "v"(&q[tid + 256*i]));
      asm volatile("s_waitcnt vmcnt(0)" ::: "memory");
#pragma unroll
      for (int i=0;i<8;i++){ zs1[tid + 256*i] = vz[i]; qs[tid + 256*i] = vq[i]; }
    }
    __syncthreads();
    {
      int r = bk*4 + wv;
      if (r < B_*T_){
        int b = r / 250, t = r - b*250;
        float s = 0.f;
#pragma unroll
        for (int i=0;i<8;i++){
          int k = i*64 + lane;
          float x = pre_s[wv*512+k] + qs[b*512+k];
          s += tanh_fast(x) * gvec_s[k];
        }
#pragma unroll
        for (int off=32; off; off>>=1) s += __shfl_xor(s, off);
        if (lane == 0) atomStoreF(&e[r], (t < hlens_s[b]) ? s : -1e30f);
      }
    }
    gbar_arrive(flags, ++gen);
    {   // overlap: pA1 = z1(u-1) @ Whh1 (consumed in phase C)
      int gd0 = wv*2, gd1 = wv*2 + 1;
      float a10[4]={}, a11[4]={};
#pragma unroll
      for (int i = 0; i < 8; ++i){
        int k = i*64 + lane;
        float w10 = whh1_s[gd0*512+k], w11 = whh1_s[gd1*512+k];
#pragma unroll
        for (int b=0;b<4;b++){
          float zv1 = zs1[b*512+k];
          a10[b] += w10*zv1; a11[b] += w11*zv1;
        }
      }
#pragma unroll
      for (int b=0;b<4;b++){
#pragma unroll
        for (int off=32; off; off>>=1){
          a10[b] += __shfl_xor(a10[b],off); a11[b] += __shfl_xor(a11[b],off);
        }
      }
      if (lane == 0){
#pragma unroll
        for (int b=0;b<4;b++){ pA1[b*8+gd0] = a10[b]; pA1[b*8+gd1] = a11[b]; }
      }
    }
    gbar_wait(flags, rel, gen);
    // ---- Phase B: softmax + gates0 -> z0' ----
    {
      int b = wv;
      const float* eb = e + b*250;
      float vals[4], w_reg[4];
      int t3 = 192 + lane;
      mall_load4f(eb + lane, eb + 64 + lane, eb + 128 + lane,
                  eb + (t3 < 250 ? t3 : 249),
                  vals[0], vals[1], vals[2], vals[3]);
      if (t3 >= 250) vals[3] = -1e30f;
      float vmax = fmaxf(fmaxf(vals[0],vals[1]), fmaxf(vals[2],vals[3]));
#pragma unroll
      for (int off=32; off; off>>=1) vmax = fmaxf(vmax, __shfl_xor(vmax, off));
      float ssum = 0.f;
#pragma unroll
      for (int i=0;i<4;i++){
        int t = i*64 + lane;
        w_reg[i] = (t < 250) ? __expf(vals[i] - vmax) : 0.f;
        ssum += w_reg[i];
      }
#pragma unroll
      for (int off=32; off; off>>=1) ssum += __shfl_xor(ssum, off);
      float inv = 1.f / ssum;
#pragma unroll
      for (int i=0;i<4;i++) w_reg[i] *= inv;

      float ag[8] = {};
#pragma unroll
      for (int i=0;i<4;i++){
        int t = i*64 + lane;
#pragma unroll
        for (int gd=0; gd<8; gd++)
          ag[gd] += w_reg[i] * hsw_s[(b*8+gd)*256 + t];
      }
#pragma unroll
      for (int gd=0; gd<8; gd++){
#pragma unroll
        for (int off=32; off; off>>=1) ag[gd] += __shfl_xor(ag[gd], off);
      }
      if (lane == 0){
#pragma unroll
        for (int gd=0; gd<8; gd++)
          gB[b*8+gd] = ag[gd] + pA0[b*8+gd] + pre0_s[(b*U_+u)*8 + gd] + bias0_s[gd];
      }
    }
    __syncthreads();
    if (tid < 8){
      int b = tid >> 1, dd = tid & 1;
      float ig = sigmoid_fast(gB[b*8 + 0 + dd]);
      float fg = sigmoid_fast(gB[b*8 + 2 + dd]);
      float gg = tanh_fast  (gB[b*8 + 4 + dd]);
      float og = sigmoid_fast(gB[b*8 + 6 + dd]);
      float cn = fg * c0_s[tid] + ig * gg;
      c0_s[tid] = cn;
      atomStoreF(&z0[b*512 + d0 + dd], og * tanh_fast(cn));
    }
    gbar(flags, rel, ++gen);   // nothing independent to overlap
    // ---- Phase C: load z0(u); gates1 + q; arrive; overlap pA0(u+1); wait
    {
      float vza[8];
#pragma unroll
      for (int i=0;i<8;i++)
        asm volatile("global_load_dword %0, %1, off sc0 sc1"
                     : "=&v"(vza[i]) : "v"(&z0[tid + 256*i]));
      asm volatile("s_waitcnt vmcnt(0)" ::: "memory");
#pragma unroll
      for (int i=0;i<8;i++) zs0[tid + 256*i] = vza[i];   // z0(u), reused next A/B
    }
    __syncthreads();
    {
      int gd0 = wv*2, gd1 = wv*2 + 1;
      float a0[4]={}, a1[4]={};
#pragma unroll
      for (int i=0;i<8;i++){
        int k = i*64 + lane;
        float w0 = wih1_s[gd0*512+k], w1 = wih1_s[gd1*512+k];
#pragma unroll
        for (int b=0;b<4;b++){
          float zv = zs0[b*512+k];
          a0[b] += w0*zv; a1[b] += w1*zv;
        }
      }
#pragma unroll
      for (int b=0;b<4;b++){
#pragma unroll
        for (int off=32; off; off>>=1){
          a0[b] += __shfl_xor(a0[b],off); a1[b] += __shfl_xor(a1[b],off);
        }
      }
      if (lane == 0){
#pragma unroll
        for (int b=0;b<4;b++){
          gC[b*8+gd0] = a0[b] + pA1[b*8+gd0] + bias1_s[gd0];
          gC[b*8+gd1] = a1[b] + pA1[b*8+gd1] + bias1_s[gd1];
        }
      }
      if (wv < 2){
        float qa[4] = {};
#pragma unroll
        for (int i=0;i<8;i++){
          int k = i*64 + lane;
          float wq = wdec_s[wv*512+k];
#pragma unroll
          for (int b=0;b<4;b++) qa[b] += wq * zs0[b*512+k];
        }
#pragma unroll
        for (int b=0;b<4;b++){
#pragma unroll
          for (int off=32; off; off>>=1) qa[b] += __shfl_xor(qa[b],off);
        }
        if (lane == 0){
#pragma unroll
          for (int b=0;b<4;b++) atomStoreF(&q[b*512 + d0 + wv], qa[b]);
        }
      }
    }
    __syncthreads();
    if (tid < 8){
      int b = tid >> 1, dd = tid & 1;
      float ig = sigmoid_fast(gC[b*8 + 0 + dd]);
      float fg = sigmoid_fast(gC[b*8 + 2 + dd]);
      float gg = tanh_fast  (gC[b*8 + 4 + dd]);
      float og = sigmoid_fast(gC[b*8 + 6 + dd]);
      float cn = fg * c1_s[tid] + ig * gg;
      c1_s[tid] = cn;
      float hn = og * tanh_fast(cn);
      atomStoreF(&z1[b*512 + d0 + dd], hn);
      h_dec[((size_t)(b*U_ + u))*512 + d0 + dd] = hn;
    }
    gbar_arrive(flags, ++gen);
    {   // overlap: pA0(u+1) = z0(u) @ Whh0 (consumed in next phase B)
      int gd0 = wv*2, gd1 = wv*2 + 1;
      float a00[4]={}, a01[4]={};
#pragma unroll
      for (int i = 0; i < 8; ++i){
        int k = i*64 + lane;
        float w00 = whh0_s[gd0*512+k], w01 = whh0_s[gd1*512+k];
#pragma unroll
        for (int b=0;b<4;b++){
          float zv0 = zs0[b*512+k];
          a00[b] += w00*zv0; a01[b] += w01*zv0;
        }
      }
#pragma unroll
      for (int b=0;b<4;b++){
#pragma unroll
        for (int off=32; off; off>>=1){
          a00[b] += __shfl_xor(a00[b],off); a01[b] += __shfl_xor(a01[b],off);
        }
      }
      if (lane == 0){
#pragma unroll
        for (int b=0;b<4;b++){ pA0[b*8+gd0] = a00[b]; pA0[b*8+gd1] = a01[b]; }
      }
    }
    gbar_wait(flags, rel, gen);
  }
}

// ---------- bf16 MFMA joint path ----------
__global__ __launch_bounds__(256) void pack_k(
    const float* __restrict__ henc, const float* __restrict__ hdec,
    unsigned short* __restrict__ P,
    const float* __restrict__ Wlin, unsigned short* __restrict__ Wb)
{
  const int NP8 = B_*T_*U_*512/8;
  int i = blockIdx.x*256 + threadIdx.x;
  if (i < NP8){
    int e = i*8;
    int k = e & 511;
    int r = e >> 9;
    int u = r % U_;
    int bt = r / U_;
    int b = bt / T_;
    const float* hp = henc + (size_t)bt*512 + k;
    const float* dp = hdec + (size_t)(b*U_ + u)*512 + k;
    unsigned int w[4];
#pragma unroll
    for (int j=0;j<4;j++){
      unsigned short lo = f2bf(tanh_fast(hp[2*j]   + dp[2*j]));
      unsigned short hi = f2bf(tanh_fast(hp[2*j+1] + dp[2*j+1]));
      w[j] = (unsigned int)lo | ((unsigned int)hi << 16);
    }
    *(ui4*)(P + e) = ui4{w[0], w[1], w[2], w[3]};
  } else {
    int j8 = i - NP8;
    if (j8 < O_*512/8){
      int e = j8*8;
      unsigned int w[4];
#pragma unroll
      for (int j=0;j<4;j++){
        unsigned short lo = f2bf(Wlin[e+2*j]);
        unsigned short hi = f2bf(Wlin[e+2*j+1]);
        w[j] = (unsigned int)lo | ((unsigned int)hi << 16);
      }
      *(ui4*)(Wb + e) = ui4{w[0], w[1], w[2], w[3]};
    }
  }
}

// joint GEMM with double-buffered LDS prefetch (T3 minimal 2-phase) + coalesced epilogue
__global__ __launch_bounds__(256) void joint_mfma_k(
    const unsigned short* __restrict__ P,
    const unsigned short* __restrict__ Wb,
    const float* __restrict__ bout,
    float* __restrict__ out)
{
  __shared__ __align__(16) char smraw[65536];   // 2 x (As 16KB + Bs 16KB)
  float* outb = (float*)smraw;                  // 32x132 f32, reused post-loop
  int tid = threadIdx.x;
  int lane = tid & 63;
  int w = tid >> 6, wr = w >> 1, wc = w & 1;
  int id = blockIdx.x;
  int bt = id % 1000;        // id, id+1000, ... (same bt-sharers) hit same XCD mod 8
  int ot = id / 1000;
  int o0 = ot * 128;
  const char* Pbase = (const char*)(P + (size_t)bt*U_*512);
  const char* Wbase = (const char*)(Wb + (size_t)o0*512);

  f32x4 acc[4][4] = {};

#define JSTAGE(bufofs, k0q) \
  { _Pragma("unroll") \
    for (int j=0;j<4;j++){ \
      int pos = (j*256 + tid)*16; \
      int row = pos >> 7; \
      int inrow = pos & 127; \
      int srcin = inrow ^ ((row & 7) << 4); \
      int arow = row < U_ ? row : (U_-1); \
      __builtin_amdgcn_global_load_lds( \
        (const __attribute__((address_space(1))) void*)(Pbase + (size_t)arow*1024 + (k0q)*2 + srcin), \
        (__attribute__((address_space(3))) void*)(smraw + (bufofs) + pos), 16, 0, 0); \
      __builtin_amdgcn_global_load_lds( \
        (const __attribute__((address_space(1))) void*)(Wbase + (size_t)row*1024 + (k0q)*2 + srcin), \
        (__attribute__((address_space(3))) void*)(smraw + (bufofs) + 16384 + pos), 16, 0, 0); \
    } }

  int cur = 0;
  JSTAGE(0, 0);
  asm volatile("s_waitcnt vmcnt(0)" ::: "memory");
  __syncthreads();
#pragma unroll
  for (int t = 0; t < 8; ++t){
    if (t < 7) JSTAGE(cur ^ 32768, (t+1)*64);   // prefetch next tile
    const char* As = smraw + cur;
    const char* Bs = smraw + cur + 16384;
#pragma unroll
    for (int kk=0; kk<2; kk++){
      bf16x8 a[4], bb[4];
#pragma unroll
      for (int m=0;m<4;m++){
        int row = wr*64 + m*16 + (lane & 15);
        int inrow = (kk*64 + (lane >> 4)*16) ^ ((row & 7) << 4);
        a[m] = *(const bf16x8*)(As + row*128 + inrow);
      }
#pragma unroll
      for (int n=0;n<4;n++){
        int row = wc*64 + n*16 + (lane & 15);
        int inrow = (kk*64 + (lane >> 4)*16) ^ ((row & 7) << 4);
        bb[n] = *(const bf16x8*)(Bs + row*128 + inrow);
      }
#pragma unroll
      for (int m=0;m<4;m++)
#pragma unroll
        for (int n=0;n<4;n++)
          acc[m][n] = __builtin_amdgcn_mfma_f32_16x16x32_bf16(a[m], bb[n], acc[m][n], 0, 0, 0);
    }
    asm volatile("s_waitcnt vmcnt(0)" ::: "memory");   // next tile landed
    __syncthreads();                                   // all done reading cur
    cur ^= 32768;
  }
#undef JSTAGE

  // epilogue: per m, stage 32(u) x 128(o) f32 tile in LDS, then coalesced stores
  float bv[4];
#pragma unroll
  for (int n=0;n<4;n++) bv[n] = bout[o0 + wc*64 + n*16 + (lane & 15)];
#pragma unroll
  for (int m=0;m<4;m++){
    __syncthreads();
#pragma unroll
    for (int n=0;n<4;n++){
      int col = wc*64 + n*16 + (lane & 15);
      int r0 = wr*16 + ((lane >> 4) << 2);
#pragma unroll
      for (int r=0;r<4;r++)
        outb[(r0+r)*132 + col] = acc[m][n][r] + bv[n];
    }
    __syncthreads();
    int row = tid >> 3;          // 0..31
    int c0  = (tid & 7) * 16;    // 0..112
    int u = (row < 16) ? (m*16 + row) : (64 + m*16 + (row - 16));
    if (u < U_){
      float* op = out + ((size_t)bt*U_ + u)*O_ + o0 + c0;
      const float* sp = &outb[row*132 + c0];
#pragma unroll
      for (int i=0;i<4;i++) *(f32x4*)(op + 4*i) = *(const f32x4*)(sp + 4*i);
    }
  }
}

extern "C" void kernel_launch(void* const* d_in, const int* in_sizes, int n_in,
                              void* d_out, int out_size, void* d_ws, size_t ws_size,
                              hipStream_t stream) {
  const float* hs       = (const float*)d_in[0];
  const int*   ys       = (const int*)  d_in[1];
  const int*   hlens    = (const int*)  d_in[2];
  const float* embed    = (const float*)d_in[3];
  const float* W_ih0    = (const float*)d_in[4];
  const float* b_ih0    = (const float*)d_in[5];
  const float* W_hh0    = (const float*)d_in[6];
  const float* b_hh0    = (const float*)d_in[7];
  const float* W_ih1    = (const float*)d_in[8];
  const float* b_ih1    = (const float*)d_in[9];
  const float* W_hh1    = (const float*)d_in[10];
  const float* b_hh1    = (const float*)d_in[11];
  const float* W_att_enc= (const float*)d_in[12];
  const float* b_att_enc= (const float*)d_in[13];
  const float* W_att_dec= (const float*)d_in[14];
  const float* gvec     = (const float*)d_in[15];
  const float* W_lin_enc= (const float*)d_in[16];
  const float* b_lin_enc= (const float*)d_in[17];
  const float* W_lin_dec= (const float*)d_in[18];
  const float* W_lin_out= (const float*)d_in[19];
  const float* b_lin_out= (const float*)d_in[20];
  float* out = (float*)d_out;

  float* w = (float*)d_ws;
  // ws layout (float offsets)
  float* z0      = w;              // 2048
  float* z1      = w + 2048;       // 2048
  float* q       = w + 4096;       // 2048
  float* e       = w + 6144;       // 1024
  int*   flags   = (int*)(w + 7168); // 256*16+16 ints (padded arrivals + rel)
  int*   rel     = flags + NBLK*16;
  float* eys     = w + 11776;      // 245760
  float* pre_enc = w + 257536;     // 512000
  float* pre0    = w + 769536;     // 983040
  float* henc    = w + 1752576;    // 512000
  float* h_dec   = w + 2264576;    // 245760
  float* hdec_p  = w + 2510336;    // 245760
  float* hsW0    = w + 2756096;    // 2048000 -> 4804096
  unsigned short* Pbf = (unsigned short*)(w + 4804096);            // 61,440,000 bf16
  unsigned short* Wbf = (unsigned short*)(w + 4804096 + 30720000); // 524,288 bf16

  gather_embed_k<<<(B_*U_*D_ + 255)/256, 256, 0, stream>>>(ys, embed, eys, flags);
  // fused: pre_enc | henc | pre0 | hsW0 (1024 blocks of 64^2 tiles)
  pre_gemms_k<<<1024, 256, 0, stream>>>(hs, eys, W_att_enc, b_att_enc,
                                        W_lin_enc, b_lin_enc, W_ih0,
                                        pre_enc, henc, pre0, hsW0);

  // LDS-resident scan (cooperative launch for co-residency; own barrier inside)
  {
    void* args[] = {
      (void*)&z0, (void*)&z1, (void*)&q, (void*)&e, (void*)&flags, (void*)&rel,
      (void*)&pre_enc, (void*)&pre0, (void*)&hsW0,
      (void*)&W_hh0, (void*)&W_ih1, (void*)&W_hh1, (void*)&W_att_dec,
      (void*)&gvec, (void*)&hlens,
      (void*)&b_ih0, (void*)&b_hh0, (void*)&b_ih1, (void*)&b_hh1,
      (void*)&h_dec
    };
    hipLaunchCooperativeKernel((const void*)scan_k, dim3(NBLK), dim3(256),
                               args, 0, stream);
  }

  // hdec = h_dec @ W_lin_dec^T
  gemm64_nt_k<<<dim3(8, 8), 256, 0, stream>>>(h_dec, 512, W_lin_dec, 512, nullptr,
                                              hdec_p, 512, B_*U_, 512, 512);
  // P = tanh(henc+hdec) bf16; Wb = bf16(W_lin_out)
  {
    const int NP8 = B_*T_*U_*512/8;
    const int NW8 = O_*512/8;
    pack_k<<<(NP8 + NW8 + 255)/256, 256, 0, stream>>>(henc, hdec_p, Pbf,
                                                      W_lin_out, Wbf);
  }
  joint_mfma_k<<<8000, 256, 0, stream>>>(Pbf, Wbf, b_lin_out, out);
}

// Round 13
// 1850.199 us; speedup vs baseline: 1.0694x; 1.0270x over previous
//
#include <hip/hip_runtime.h>

#define B_ 4
#define T_ 250
#define U_ 120
#define D_ 512
#define G_ 2048   // 4*D (gates)
#define O_ 1024   // odim
#define NBLK 256

typedef __attribute__((ext_vector_type(8))) short bf16x8;
typedef __attribute__((ext_vector_type(4))) float f32x4;
typedef __attribute__((ext_vector_type(4))) unsigned int ui4;

__device__ __forceinline__ float tanh_fast(float x){
  float e = __expf(2.f*x);
  return 1.f - 2.f/(e + 1.f);
}
__device__ __forceinline__ float sigmoid_fast(float x){
  return 1.f/(1.f + __expf(-x));
}
__device__ __forceinline__ unsigned short f2bf(float x){
  unsigned int u = __float_as_uint(x);
  unsigned int r = (u + 0x7FFFu + ((u >> 16) & 1u)) >> 16;
  return (unsigned short)r;
}

// MALL-coherent single-value ops
__device__ __forceinline__ void atomStoreF(float* p, float v){
  __hip_atomic_store(p, v, __ATOMIC_RELAXED, __HIP_MEMORY_SCOPE_AGENT);
}
__device__ __forceinline__ void mall_load4f(const float* p0, const float* p1,
    const float* p2, const float* p3, float& v0, float& v1, float& v2, float& v3){
  asm volatile(
    "global_load_dword %0, %4, off sc0 sc1\n\t"
    "global_load_dword %1, %5, off sc0 sc1\n\t"
    "global_load_dword %2, %6, off sc0 sc1\n\t"
    "global_load_dword %3, %7, off sc0 sc1\n\t"
    "s_waitcnt vmcnt(0)"
    : "=&v"(v0), "=&v"(v1), "=&v"(v2), "=&v"(v3)
    : "v"(p0), "v"(p1), "v"(p2), "v"(p3)
    : "memory");
}

// barrier v4: split arrive/wait so independent compute hides the round trips.
__device__ __forceinline__ void gbar_arrive(int* flags, int gen){
  __syncthreads();
  if (threadIdx.x == 0){
    asm volatile("s_waitcnt vmcnt(0)" ::: "memory");
    __hip_atomic_store(&flags[blockIdx.x*16], gen, __ATOMIC_RELAXED,
                       __HIP_MEMORY_SCOPE_AGENT);
  }
}
__device__ __forceinline__ void gbar_wait(int* flags, int* rel, int gen){
  if (blockIdx.x == 0){
    if (threadIdx.x < 64){
      int l = threadIdx.x;
      const int* p0 = flags + (l*4+0)*16;
      const int* p1 = flags + (l*4+1)*16;
      const int* p2 = flags + (l*4+2)*16;
      const int* p3 = flags + (l*4+3)*16;
      long c = 0;
      while (true){
        int f0,f1,f2,f3;
        asm volatile(
          "global_load_dword %0, %4, off sc0 sc1\n\t"
          "global_load_dword %1, %5, off sc0 sc1\n\t"
          "global_load_dword %2, %6, off sc0 sc1\n\t"
          "global_load_dword %3, %7, off sc0 sc1\n\t"
          "s_waitcnt vmcnt(0)"
          : "=&v"(f0),"=&v"(f1),"=&v"(f2),"=&v"(f3)
          : "v"(p0), "v"(p1), "v"(p2), "v"(p3)
          : "memory");
        int m0 = f0 < f1 ? f0 : f1;
        int m1 = f2 < f3 ? f2 : f3;
        int mm = m0 < m1 ? m0 : m1;
        if (__all(mm >= gen)) break;
        if (++c > (1L<<22)) break;   // anti-hang valve
      }
      if (threadIdx.x == 0)
        __hip_atomic_store(rel, gen, __ATOMIC_RELAXED,
                           __HIP_MEMORY_SCOPE_AGENT);
    }
  } else {
    if (threadIdx.x == 0){
      long c = 0;
      while (__hip_atomic_load(rel, __ATOMIC_RELAXED,
                               __HIP_MEMORY_SCOPE_AGENT) < gen){
        if (++c > (1L<<22)) break;
      }
    }
  }
  __syncthreads();
}
__device__ __forceinline__ void gbar(int* flags, int* rel, int gen){
  gbar_arrive(flags, gen);
  gbar_wait(flags, rel, gen);
}

// ---------- 64x64 GEMM bodies ----------
__device__ __forceinline__ void gemm64_nt_body(float* smem,
  const float* __restrict__ A, int lda, const float* __restrict__ B, int ldb,
  const float* __restrict__ bias, float* __restrict__ C, int ldc,
  int M, int N, int K, int bx, int by)
{
  float (*As)[65] = (float(*)[65])smem;
  float (*Bs)[65] = (float(*)[65])(smem + 16*65);
  int tid = threadIdx.x;
  int m0 = by*64, n0 = bx*64;
  int tx = tid & 15, ty = tid >> 4;
  float acc[4][4] = {};
  for (int k0 = 0; k0 < K; k0 += 16){
#pragma unroll
    for (int i=0;i<4;i++){
      int e = tid + 256*i;
      int mm = e >> 4, kk = e & 15;
      int mg = m0 + mm;
      As[kk][mm] = (mg < M) ? A[(size_t)mg*lda + k0 + kk] : 0.f;
      int ng = n0 + mm;
      Bs[kk][mm] = (ng < N) ? B[(size_t)ng*ldb + k0 + kk] : 0.f;
    }
    __syncthreads();
#pragma unroll
    for (int kk=0;kk<16;kk++){
      float av[4], bv[4];
#pragma unroll
      for (int i=0;i<4;i++) av[i] = As[kk][ty*4+i];
#pragma unroll
      for (int j=0;j<4;j++) bv[j] = Bs[kk][tx*4+j];
#pragma unroll
      for (int i=0;i<4;i++)
#pragma unroll
        for (int j=0;j<4;j++) acc[i][j] += av[i]*bv[j];
    }
    __syncthreads();
  }
#pragma unroll
  for (int i=0;i<4;i++){
    int m = m0 + ty*4 + i;
    if (m < M){
#pragma unroll
      for (int j=0;j<4;j++){
        int n = n0 + tx*4 + j;
        if (n < N) C[(size_t)m*ldc + n] = acc[i][j] + (bias ? bias[n] : 0.f);
      }
    }
  }
}

// nt body with A rows gathered through embed[ys[row]]
__device__ __forceinline__ void gemm64_nt_embed_body(float* smem,
  const int* __restrict__ ys, const float* __restrict__ embed,
  const float* __restrict__ B, int ldb,
  float* __restrict__ C, int ldc,
  int M, int N, int K, int bx, int by)
{
  float (*As)[65] = (float(*)[65])smem;
  float (*Bs)[65] = (float(*)[65])(smem + 16*65);
  int tid = threadIdx.x;
  int m0 = by*64, n0 = bx*64;
  int tx = tid & 15, ty = tid >> 4;
  int yrow[4];
#pragma unroll
  for (int i=0;i<4;i++){
    int e = tid + 256*i;
    int mg = m0 + (e >> 4);
    yrow[i] = (mg < M) ? ys[mg] : -1;
  }
  float acc[4][4] = {};
  for (int k0 = 0; k0 < K; k0 += 16){
#pragma unroll
    for (int i=0;i<4;i++){
      int e = tid + 256*i;
      int mm = e >> 4, kk = e & 15;
      As[kk][mm] = (yrow[i] >= 0) ? embed[(size_t)yrow[i]*512 + k0 + kk] : 0.f;
      int ng = n0 + mm;
      Bs[kk][mm] = (ng < N) ? B[(size_t)ng*ldb + k0 + kk] : 0.f;
    }
    __syncthreads();
#pragma unroll
    for (int kk=0;kk<16;kk++){
      float av[4], bv[4];
#pragma unroll
      for (int i=0;i<4;i++) av[i] = As[kk][ty*4+i];
#pragma unroll
      for (int j=0;j<4;j++) bv[j] = Bs[kk][tx*4+j];
#pragma unroll
      for (int i=0;i<4;i++)
#pragma unroll
        for (int j=0;j<4;j++) acc[i][j] += av[i]*bv[j];
    }
    __syncthreads();
  }
#pragma unroll
  for (int i=0;i<4;i++){
    int m = m0 + ty*4 + i;
    if (m < M){
#pragma unroll
      for (int j=0;j<4;j++){
        int n = n0 + tx*4 + j;
        if (n < N) C[(size_t)m*ldc + n] = acc[i][j];
      }
    }
  }
}

__device__ __forceinline__ void gemm64_nn_body(float* smem,
  const float* __restrict__ A, int lda, const float* __restrict__ B, int ldb,
  const float* __restrict__ bias, float* __restrict__ C, int ldc,
  int M, int N, int K, int bx, int by)
{
  float (*As)[65] = (float(*)[65])smem;
  float (*Bs)[65] = (float(*)[65])(smem + 16*65);
  int tid = threadIdx.x;
  int m0 = by*64, n0 = bx*64;
  int tx = tid & 15, ty = tid >> 4;
  float acc[4][4] = {};
  for (int k0 = 0; k0 < K; k0 += 16){
#pragma unroll
    for (int i=0;i<4;i++){
      int e = tid + 256*i;
      int mm = e >> 4, kk = e & 15;
      int mg = m0 + mm;
      As[kk][mm] = (mg < M) ? A[(size_t)mg*lda + k0 + kk] : 0.f;
      int nn = e & 63, kk2 = e >> 6;
      int ng = n0 + nn;
      Bs[kk2][nn] = (ng < N) ? B[(size_t)(k0+kk2)*ldb + ng] : 0.f;
    }
    __syncthreads();
#pragma unroll
    for (int kk=0;kk<16;kk++){
      float av[4], bv[4];
#pragma unroll
      for (int i=0;i<4;i++) av[i] = As[kk][ty*4+i];
#pragma unroll
      for (int j=0;j<4;j++) bv[j] = Bs[kk][tx*4+j];
#pragma unroll
      for (int i=0;i<4;i++)
#pragma unroll
        for (int j=0;j<4;j++) acc[i][j] += av[i]*bv[j];
    }
    __syncthreads();
  }
#pragma unroll
  for (int i=0;i<4;i++){
    int m = m0 + ty*4 + i;
    if (m < M){
#pragma unroll
      for (int j=0;j<4;j++){
        int n = n0 + tx*4 + j;
        if (n < N) C[(size_t)m*ldc + n] = acc[i][j] + (bias ? bias[n] : 0.f);
      }
    }
  }
}

// fused precompute + flags init + Wb conversion. 1056 blocks:
// [0,128): pre_enc nn | [128,256): henc nt | [256,512): pre0 nt (embed-gather)
// [512,1024): hsW0 nt | [1024,1056): Wbf convert (+flags init in 1024)
__global__ __launch_bounds__(256) void pre_gemms_k(
  const float* __restrict__ hs, const int* __restrict__ ys,
  const float* __restrict__ embed,
  const float* __restrict__ W_att_enc, const float* __restrict__ b_att_enc,
  const float* __restrict__ W_lin_enc, const float* __restrict__ b_lin_enc,
  const float* __restrict__ W_ih0,
  const float* __restrict__ W_lin_out, unsigned short* __restrict__ Wbf,
  int* __restrict__ flags,
  float* __restrict__ pre_enc, float* __restrict__ henc,
  float* __restrict__ pre0, float* __restrict__ hsW0)
{
  __shared__ float smem[2*16*65];
  int id = blockIdx.x;
  if (id < 128){
    gemm64_nn_body(smem, hs,512, W_att_enc,512, b_att_enc, pre_enc,512,
                   B_*T_,512,512, id & 7, id >> 3);
  } else if (id < 256){
    id -= 128;
    gemm64_nt_body(smem, hs,512, W_lin_enc,512, b_lin_enc, henc,512,
                   B_*T_,512,512, id & 7, id >> 3);
  } else if (id < 512){
    id -= 256;
    gemm64_nt_embed_body(smem, ys, embed, W_ih0,1024, pre0,2048,
                         B_*U_,2048,512, id & 31, id >> 5);
  } else if (id < 1024){
    id -= 512;
    gemm64_nt_body(smem, hs,512, W_ih0+512,1024, nullptr, hsW0,2048,
                   B_*T_,2048,512, id & 31, id >> 5);
  } else {
    int tid = threadIdx.x;
    if (id == 1024){
      for (int i = tid; i < NBLK*16 + 16; i += 256)
        __hip_atomic_store(&flags[i], 0, __ATOMIC_RELAXED,
                           __HIP_MEMORY_SCOPE_AGENT);
    }
    int i = (id - 1024)*256 + tid;   // 8192 threads over 65536 chunks
    for (int j8 = i; j8 < O_*512/8; j8 += 8192){
      int e = j8*8;
      unsigned int w[4];
#pragma unroll
      for (int j=0;j<4;j++){
        unsigned short lo = f2bf(W_lin_out[e+2*j]);
        unsigned short hi = f2bf(W_lin_out[e+2*j+1]);
        w[j] = (unsigned int)lo | ((unsigned int)hi << 16);
      }
      *(ui4*)(Wbf + e) = ui4{w[0], w[1], w[2], w[3]};
    }
  }
}

// ---------- LDS-resident scan, barrier v4 with overlap; hdec fused in B-window
__global__ __launch_bounds__(256) void scan_k(
    float* __restrict__ z0, float* __restrict__ z1,
    float* __restrict__ q,  float* __restrict__ e,
    int* __restrict__ flags, int* __restrict__ rel,
    const float* __restrict__ pre_enc, const float* __restrict__ pre0,
    const float* __restrict__ hsW0,
    const float* __restrict__ W_hh0, const float* __restrict__ W_ih1,
    const float* __restrict__ W_hh1, const float* __restrict__ W_att_dec,
    const float* __restrict__ W_lin_dec,
    const float* __restrict__ gvec, const int* __restrict__ hlens,
    const float* __restrict__ b_ih0, const float* __restrict__ b_hh0,
    const float* __restrict__ b_ih1, const float* __restrict__ b_hh1,
    float* __restrict__ hdec_p)
{
  int bk = blockIdx.x, tid = threadIdx.x;
  int lane = tid & 63, wv = tid >> 6;
  int d0 = bk * 2;

  __shared__ float whh0_s[8*512];   // [gd][k]
  __shared__ float whh1_s[8*512];
  __shared__ float wih1_s[8*512];
  __shared__ float wdec_s[2*512];   // [delta][k]
  __shared__ float wld_s[2*512];    // W_lin_dec rows d0, d0+1
  __shared__ float hsw_s[4*8*256];  // [b][gd][t(pad 256)]
  __shared__ float pre0_s[480*8];   // [(b*120+u)][gd]
  __shared__ float pre_s[4*512];    // e-rows
  __shared__ float gvec_s[512];
  __shared__ float zs0[2048], zs1[2048], qs[2048];
  __shared__ float pA0[32], pA1[32], gB[32], gC[32];
  __shared__ float bias0_s[8], bias1_s[8], c0_s[8], c1_s[8];
  __shared__ int hlens_s[4];

  // ---- one-time LDS load ----
  for (int idx = tid; idx < 8*512; idx += 256){
    int gd = idx >> 9, k = idx & 511;
    int j = (gd >> 1)*512 + d0 + (gd & 1);
    whh0_s[idx] = W_hh0[(size_t)j*512 + k];
    whh1_s[idx] = W_hh1[(size_t)j*512 + k];
    wih1_s[idx] = W_ih1[(size_t)j*512 + k];
  }
  for (int idx = tid; idx < 2*512; idx += 256){
    int dd = idx >> 9, k = idx & 511;
    wdec_s[idx] = W_att_dec[(size_t)k*512 + d0 + dd];
    wld_s[idx]  = W_lin_dec[(size_t)(d0+dd)*512 + k];
  }
  for (int idx = tid; idx < 4*1000; idx += 256){
    int gp = idx & 3, tg = idx >> 2;
    int b = tg / 250, t = tg - b*250;
    const float2 v = *(const float2*)(hsW0 + (size_t)tg*G_ + gp*512 + d0);
    hsw_s[(b*8 + gp*2 + 0)*256 + t] = v.x;
    hsw_s[(b*8 + gp*2 + 1)*256 + t] = v.y;
  }
  for (int idx = tid; idx < 4*8*6; idx += 256){   // zero t-pad 250..255
    int t = 250 + (idx % 6), bg = idx / 6;
    hsw_s[bg*256 + t] = 0.f;
  }
  for (int idx = tid; idx < 480*4; idx += 256){
    int gp = idx & 3, r = idx >> 2;
    const float2 v = *(const float2*)(pre0 + (size_t)r*G_ + gp*512 + d0);
    pre0_s[r*8 + gp*2 + 0] = v.x;
    pre0_s[r*8 + gp*2 + 1] = v.y;
  }
  for (int idx = tid; idx < 4*512; idx += 256){
    int r = bk*4 + (idx >> 9);
    pre_s[idx] = (r < B_*T_) ? pre_enc[(size_t)r*512 + (idx & 511)] : 0.f;
  }
  for (int idx = tid; idx < 512; idx += 256) gvec_s[idx] = gvec[idx];
  for (int idx = tid; idx < 2048; idx += 256) zs0[idx] = 0.f;   // z0(-1) = 0
  if (tid < 4) hlens_s[tid] = hlens[tid];
  if (tid < 32){ pA0[tid] = 0.f; }   // z0(-1)@Whh0 = 0
  if (tid < 8){
    int j = ((tid >> 1))*512 + d0 + (tid & 1);
    bias0_s[tid] = b_ih0[j] + b_hh0[j];
    bias1_s[tid] = b_ih1[j] + b_hh1[j];
    c0_s[tid] = 0.f; c1_s[tid] = 0.f;
    int b = tid >> 1, d = d0 + (tid & 1);
    atomStoreF(&z1[b*512 + d], 0.f);
    atomStoreF(&q [b*512 + d], 0.f);
  }
  int gen = 0;
  gbar(flags, rel, ++gen);

  for (int u = 0; u < U_; ++u){
    // ---- Phase A: load z1(u-1),q(u-1); compute e(u); arrive; overlap pA1; wait
    {
      float vz[8], vq[8];
#pragma unroll
      for (int i=0;i<8;i++)
        asm volatile("global_load_dword %0, %1, off sc0 sc1"
                     : "=&v"(vz[i]) : "v"(&z1[tid + 256*i]));
#pragma unroll
      for (int i=0;i<8;i++)
        asm volatile("global_load_dword %0, %1, off sc0 sc1"
                     : "=&v"(vq[i]) : "v"(&q[tid + 256*i]));
      asm volatile("s_waitcnt vmcnt(0)" ::: "memory");
#pragma unroll
      for (int i=0;i<8;i++){ zs1[tid + 256*i] = vz[i]; qs[tid + 256*i] = vq[i]; }
    }
    __syncthreads();
    {
      int r = bk*4 + wv;
      if (r < B_*T_){
        int b = r / 250, t = r - b*250;
        float s = 0.f;
#pragma unroll
        for (int i=0;i<8;i++){
          int k = i*64 + lane;
          float x = pre_s[wv*512+k] + qs[b*512+k];
          s += tanh_fast(x) * gvec_s[k];
        }
#pragma unroll
        for (int off=32; off; off>>=1) s += __shfl_xor(s, off);
        if (lane == 0) atomStoreF(&e[r], (t < hlens_s[b]) ? s : -1e30f);
      }
    }
    gbar_arrive(flags, ++gen);
    {   // overlap: pA1 = z1(u-1) @ Whh1 (consumed in phase C)
      int gd0 = wv*2, gd1 = wv*2 + 1;
      float a10[4]={}, a11[4]={};
#pragma unroll
      for (int i = 0; i < 8; ++i){
        int k = i*64 + lane;
        float w10 = whh1_s[gd0*512+k], w11 = whh1_s[gd1*512+k];
#pragma unroll
        for (int b=0;b<4;b++){
          float zv1 = zs1[b*512+k];
          a10[b] += w10*zv1; a11[b] += w11*zv1;
        }
      }
#pragma unroll
      for (int b=0;b<4;b++){
#pragma unroll
        for (int off=32; off; off>>=1){
          a10[b] += __shfl_xor(a10[b],off); a11[b] += __shfl_xor(a11[b],off);
        }
      }
      if (lane == 0){
#pragma unroll
        for (int b=0;b<4;b++){ pA1[b*8+gd0] = a10[b]; pA1[b*8+gd1] = a11[b]; }
      }
    }
    gbar_wait(flags, rel, gen);
    // ---- Phase B: softmax + gates0 -> z0' ----
    {
      int b = wv;
      const float* eb = e + b*250;
      float vals[4], w_reg[4];
      int t3 = 192 + lane;
      mall_load4f(eb + lane, eb + 64 + lane, eb + 128 + lane,
                  eb + (t3 < 250 ? t3 : 249),
                  vals[0], vals[1], vals[2], vals[3]);
      if (t3 >= 250) vals[3] = -1e30f;
      float vmax = fmaxf(fmaxf(vals[0],vals[1]), fmaxf(vals[2],vals[3]));
#pragma unroll
      for (int off=32; off; off>>=1) vmax = fmaxf(vmax, __shfl_xor(vmax, off));
      float ssum = 0.f;
#pragma unroll
      for (int i=0;i<4;i++){
        int t = i*64 + lane;
        w_reg[i] = (t < 250) ? __expf(vals[i] - vmax) : 0.f;
        ssum += w_reg[i];
      }
#pragma unroll
      for (int off=32; off; off>>=1) ssum += __shfl_xor(ssum, off);
      float inv = 1.f / ssum;
#pragma unroll
      for (int i=0;i<4;i++) w_reg[i] *= inv;

      float ag[8] = {};
#pragma unroll
      for (int i=0;i<4;i++){
        int t = i*64 + lane;
#pragma unroll
        for (int gd=0; gd<8; gd++)
          ag[gd] += w_reg[i] * hsw_s[(b*8+gd)*256 + t];
      }
#pragma unroll
      for (int gd=0; gd<8; gd++){
#pragma unroll
        for (int off=32; off; off>>=1) ag[gd] += __shfl_xor(ag[gd], off);
      }
      if (lane == 0){
#pragma unroll
        for (int gd=0; gd<8; gd++)
          gB[b*8+gd] = ag[gd] + pA0[b*8+gd] + pre0_s[(b*U_+u)*8 + gd] + bias0_s[gd];
      }
    }
    __syncthreads();
    if (tid < 8){
      int b = tid >> 1, dd = tid & 1;
      float ig = sigmoid_fast(gB[b*8 + 0 + dd]);
      float fg = sigmoid_fast(gB[b*8 + 2 + dd]);
      float gg = tanh_fast  (gB[b*8 + 4 + dd]);
      float og = sigmoid_fast(gB[b*8 + 6 + dd]);
      float cn = fg * c0_s[tid] + ig * gg;
      c0_s[tid] = cn;
      atomStoreF(&z0[b*512 + d0 + dd], og * tanh_fast(cn));
    }
    gbar_arrive(flags, ++gen);
    if (u > 0){   // overlap: hdec_p[b, u-1, d0:d0+2] = z1(u-1) @ W_lin_dec^T
      int b = wv;
      float a0 = 0.f, a1 = 0.f;
#pragma unroll
      for (int i=0;i<8;i++){
        int k = i*64 + lane;
        float zv = zs1[b*512+k];
        a0 += zv * wld_s[k];
        a1 += zv * wld_s[512+k];
      }
#pragma unroll
      for (int off=32; off; off>>=1){
        a0 += __shfl_xor(a0,off); a1 += __shfl_xor(a1,off);
      }
      if (lane == 0){
        size_t base = ((size_t)(b*U_ + (u-1)))*512 + d0;
        hdec_p[base]   = a0;
        hdec_p[base+1] = a1;
      }
    }
    gbar_wait(flags, rel, gen);
    // ---- Phase C: load z0(u); gates1 + q; arrive; overlap pA0(u+1); wait
    {
      float vza[8];
#pragma unroll
      for (int i=0;i<8;i++)
        asm volatile("global_load_dword %0, %1, off sc0 sc1"
                     : "=&v"(vza[i]) : "v"(&z0[tid + 256*i]));
      asm volatile("s_waitcnt vmcnt(0)" ::: "memory");
#pragma unroll
      for (int i=0;i<8;i++) zs0[tid + 256*i] = vza[i];   // z0(u), reused next A/B
    }
    __syncthreads();
    {
      int gd0 = wv*2, gd1 = wv*2 + 1;
      float a0[4]={}, a1[4]={};
#pragma unroll
      for (int i=0;i<8;i++){
        int k = i*64 + lane;
        float w0 = wih1_s[gd0*512+k], w1 = wih1_s[gd1*512+k];
#pragma unroll
        for (int b=0;b<4;b++){
          float zv = zs0[b*512+k];
          a0[b] += w0*zv; a1[b] += w1*zv;
        }
      }
#pragma unroll
      for (int b=0;b<4;b++){
#pragma unroll
        for (int off=32; off; off>>=1){
          a0[b] += __shfl_xor(a0[b],off); a1[b] += __shfl_xor(a1[b],off);
        }
      }
      if (lane == 0){
#pragma unroll
        for (int b=0;b<4;b++){
          gC[b*8+gd0] = a0[b] + pA1[b*8+gd0] + bias1_s[gd0];
          gC[b*8+gd1] = a1[b] + pA1[b*8+gd1] + bias1_s[gd1];
        }
      }
      if (wv < 2){
        float qa[4] = {};
#pragma unroll
        for (int i=0;i<8;i++){
          int k = i*64 + lane;
          float wq = wdec_s[wv*512+k];
#pragma unroll
          for (int b=0;b<4;b++) qa[b] += wq * zs0[b*512+k];
        }
#pragma unroll
        for (int b=0;b<4;b++){
#pragma unroll
          for (int off=32; off; off>>=1) qa[b] += __shfl_xor(qa[b],off);
        }
        if (lane == 0){
#pragma unroll
          for (int b=0;b<4;b++) atomStoreF(&q[b*512 + d0 + wv], qa[b]);
        }
      }
    }
    __syncthreads();
    if (tid < 8){
      int b = tid >> 1, dd = tid & 1;
      float ig = sigmoid_fast(gC[b*8 + 0 + dd]);
      float fg = sigmoid_fast(gC[b*8 + 2 + dd]);
      float gg = tanh_fast  (gC[b*8 + 4 + dd]);
      float og = sigmoid_fast(gC[b*8 + 6 + dd]);
      float cn = fg * c1_s[tid] + ig * gg;
      c1_s[tid] = cn;
      atomStoreF(&z1[b*512 + d0 + dd], og * tanh_fast(cn));
    }
    gbar_arrive(flags, ++gen);
    {   // overlap: pA0(u+1) = z0(u) @ Whh0 (consumed in next phase B)
      int gd0 = wv*2, gd1 = wv*2 + 1;
      float a00[4]={}, a01[4]={};
#pragma unroll
      for (int i = 0; i < 8; ++i){
        int k = i*64 + lane;
        float w00 = whh0_s[gd0*512+k], w01 = whh0_s[gd1*512+k];
#pragma unroll
        for (int b=0;b<4;b++){
          float zv0 = zs0[b*512+k];
          a00[b] += w00*zv0; a01[b] += w01*zv0;
        }
      }
#pragma unroll
      for (int b=0;b<4;b++){
#pragma unroll
        for (int off=32; off; off>>=1){
          a00[b] += __shfl_xor(a00[b],off); a01[b] += __shfl_xor(a01[b],off);
        }
      }
      if (lane == 0){
#pragma unroll
        for (int b=0;b<4;b++){ pA0[b*8+gd0] = a00[b]; pA0[b*8+gd1] = a01[b]; }
      }
    }
    gbar_wait(flags, rel, gen);
  }

  // ---- tail: hdec row 119 from z1(119) (final barrier made z1 visible) ----
  {
    float vz[8];
#pragma unroll
    for (int i=0;i<8;i++)
      asm volatile("global_load_dword %0, %1, off sc0 sc1"
                   : "=&v"(vz[i]) : "v"(&z1[tid + 256*i]));
    asm volatile("s_waitcnt vmcnt(0)" ::: "memory");
#pragma unroll
    for (int i=0;i<8;i++) zs1[tid + 256*i] = vz[i];
  }
  __syncthreads();
  {
    int b = wv;
    float a0 = 0.f, a1 = 0.f;
#pragma unroll
    for (int i=0;i<8;i++){
      int k = i*64 + lane;
      float zv = zs1[b*512+k];
      a0 += zv * wld_s[k];
      a1 += zv * wld_s[512+k];
    }
#pragma unroll
    for (int off=32; off; off>>=1){
      a0 += __shfl_xor(a0,off); a1 += __shfl_xor(a1,off);
    }
    if (lane == 0){
      size_t base = ((size_t)(b*U_ + (U_-1)))*512 + d0;
      hdec_p[base]   = a0;
      hdec_p[base+1] = a1;
    }
  }
}

// ---------- bf16 MFMA joint path ----------
// tanh-pack P only (W conversion moved to pre_gemms)
__global__ __launch_bounds__(256) void pack_k(
    const float* __restrict__ henc, const float* __restrict__ hdec,
    unsigned short* __restrict__ P)
{
  const int NP8 = B_*T_*U_*512/8;
  int i = blockIdx.x*256 + threadIdx.x;
  if (i >= NP8) return;
  int e = i*8;
  int k = e & 511;
  int r = e >> 9;
  int u = r % U_;
  int bt = r / U_;
  int b = bt / T_;
  const float* hp = henc + (size_t)bt*512 + k;
  const float* dp = hdec + (size_t)(b*U_ + u)*512 + k;
  unsigned int w[4];
#pragma unroll
  for (int j=0;j<4;j++){
    unsigned short lo = f2bf(tanh_fast(hp[2*j]   + dp[2*j]));
    unsigned short hi = f2bf(tanh_fast(hp[2*j+1] + dp[2*j+1]));
    w[j] = (unsigned int)lo | ((unsigned int)hi << 16);
  }
  *(ui4*)(P + e) = ui4{w[0], w[1], w[2], w[3]};
}

// joint GEMM with double-buffered LDS prefetch + coalesced epilogue
__global__ __launch_bounds__(256) void joint_mfma_k(
    const unsigned short* __restrict__ P,
    const unsigned short* __restrict__ Wb,
    const float* __restrict__ bout,
    float* __restrict__ out)
{
  __shared__ __align__(16) char smraw[65536];   // 2 x (As 16KB + Bs 16KB)
  float* outb = (float*)smraw;                  // 32x132 f32, reused post-loop
  int tid = threadIdx.x;
  int lane = tid & 63;
  int w = tid >> 6, wr = w >> 1, wc = w & 1;
  int id = blockIdx.x;
  int bt = id % 1000;
  int ot = id / 1000;
  int o0 = ot * 128;
  const char* Pbase = (const char*)(P + (size_t)bt*U_*512);
  const char* Wbase = (const char*)(Wb + (size_t)o0*512);

  f32x4 acc[4][4] = {};

#define JSTAGE(bufofs, k0q) \
  { _Pragma("unroll") \
    for (int j=0;j<4;j++){ \
      int pos = (j*256 + tid)*16; \
      int row = pos >> 7; \
      int inrow = pos & 127; \
      int srcin = inrow ^ ((row & 7) << 4); \
      int arow = row < U_ ? row : (U_-1); \
      __builtin_amdgcn_global_load_lds( \
        (const __attribute__((address_space(1))) void*)(Pbase + (size_t)arow*1024 + (k0q)*2 + srcin), \
        (__attribute__((address_space(3))) void*)(smraw + (bufofs) + pos), 16, 0, 0); \
      __builtin_amdgcn_global_load_lds( \
        (const __attribute__((address_space(1))) void*)(Wbase + (size_t)row*1024 + (k0q)*2 + srcin), \
        (__attribute__((address_space(3))) void*)(smraw + (bufofs) + 16384 + pos), 16, 0, 0); \
    } }

  int cur = 0;
  JSTAGE(0, 0);
  asm volatile("s_waitcnt vmcnt(0)" ::: "memory");
  __syncthreads();
#pragma unroll
  for (int t = 0; t < 8; ++t){
    if (t < 7) JSTAGE(cur ^ 32768, (t+1)*64);
    const char* As = smraw + cur;
    const char* Bs = smraw + cur + 16384;
#pragma unroll
    for (int kk=0; kk<2; kk++){
      bf16x8 a[4], bb[4];
#pragma unroll
      for (int m=0;m<4;m++){
        int row = wr*64 + m*16 + (lane & 15);
        int inrow = (kk*64 + (lane >> 4)*16) ^ ((row & 7) << 4);
        a[m] = *(const bf16x8*)(As + row*128 + inrow);
      }
#pragma unroll
      for (int n=0;n<4;n++){
        int row = wc*64 + n*16 + (lane & 15);
        int inrow = (kk*64 + (lane >> 4)*16) ^ ((row & 7) << 4);
        bb[n] = *(const bf16x8*)(Bs + row*128 + inrow);
      }
#pragma unroll
      for (int m=0;m<4;m++)
#pragma unroll
        for (int n=0;n<4;n++)
          acc[m][n] = __builtin_amdgcn_mfma_f32_16x16x32_bf16(a[m], bb[n], acc[m][n], 0, 0, 0);
    }
    asm volatile("s_waitcnt vmcnt(0)" ::: "memory");
    __syncthreads();
    cur ^= 32768;
  }
#undef JSTAGE

  // epilogue: per m, stage 32(u) x 128(o) f32 tile in LDS, then coalesced stores
  float bv[4];
#pragma unroll
  for (int n=0;n<4;n++) bv[n] = bout[o0 + wc*64 + n*16 + (lane & 15)];
#pragma unroll
  for (int m=0;m<4;m++){
    __syncthreads();
#pragma unroll
    for (int n=0;n<4;n++){
      int col = wc*64 + n*16 + (lane & 15);
      int r0 = wr*16 + ((lane >> 4) << 2);
#pragma unroll
      for (int r=0;r<4;r++)
        outb[(r0+r)*132 + col] = acc[m][n][r] + bv[n];
    }
    __syncthreads();
    int row = tid >> 3;          // 0..31
    int c0  = (tid & 7) * 16;    // 0..112
    int u = (row < 16) ? (m*16 + row) : (64 + m*16 + (row - 16));
    if (u < U_){
      float* op = out + ((size_t)bt*U_ + u)*O_ + o0 + c0;
      const float* sp = &outb[row*132 + c0];
#pragma unroll
      for (int i=0;i<4;i++) *(f32x4*)(op + 4*i) = *(const f32x4*)(sp + 4*i);
    }
  }
}

extern "C" void kernel_launch(void* const* d_in, const int* in_sizes, int n_in,
                              void* d_out, int out_size, void* d_ws, size_t ws_size,
                              hipStream_t stream) {
  const float* hs       = (const float*)d_in[0];
  const int*   ys       = (const int*)  d_in[1];
  const int*   hlens    = (const int*)  d_in[2];
  const float* embed    = (const float*)d_in[3];
  const float* W_ih0    = (const float*)d_in[4];
  const float* b_ih0    = (const float*)d_in[5];
  const float* W_hh0    = (const float*)d_in[6];
  const float* b_hh0    = (const float*)d_in[7];
  const float* W_ih1    = (const float*)d_in[8];
  const float* b_ih1    = (const float*)d_in[9];
  const float* W_hh1    = (const float*)d_in[10];
  const float* b_hh1    = (const float*)d_in[11];
  const float* W_att_enc= (const float*)d_in[12];
  const float* b_att_enc= (const float*)d_in[13];
  const float* W_att_dec= (const float*)d_in[14];
  const float* gvec     = (const float*)d_in[15];
  const float* W_lin_enc= (const float*)d_in[16];
  const float* b_lin_enc= (const float*)d_in[17];
  const float* W_lin_dec= (const float*)d_in[18];
  const float* W_lin_out= (const float*)d_in[19];
  const float* b_lin_out= (const float*)d_in[20];
  float* out = (float*)d_out;

  float* w = (float*)d_ws;
  // ws layout (float offsets)
  float* z0      = w;              // 2048
  float* z1      = w + 2048;       // 2048
  float* q       = w + 4096;       // 2048
  float* e       = w + 6144;       // 1024
  int*   flags   = (int*)(w + 7168); // 256*16+16 ints (padded arrivals + rel)
  int*   rel     = flags + NBLK*16;
  float* pre_enc = w + 257536;     // 512000
  float* pre0    = w + 769536;     // 983040
  float* henc    = w + 1752576;    // 512000
  float* hdec_p  = w + 2510336;    // 245760
  float* hsW0    = w + 2756096;    // 2048000 -> 4804096
  unsigned short* Pbf = (unsigned short*)(w + 4804096);            // 61,440,000 bf16
  unsigned short* Wbf = (unsigned short*)(w + 4804096 + 30720000); // 524,288 bf16

  // fused: pre_enc | henc | pre0(embed-gather) | hsW0 | Wbf + flags
  pre_gemms_k<<<1056, 256, 0, stream>>>(hs, ys, embed, W_att_enc, b_att_enc,
                                        W_lin_enc, b_lin_enc, W_ih0,
                                        W_lin_out, Wbf, flags,
                                        pre_enc, henc, pre0, hsW0);

  // LDS-resident scan (cooperative launch for co-residency; own barrier inside)
  {
    void* args[] = {
      (void*)&z0, (void*)&z1, (void*)&q, (void*)&e, (void*)&flags, (void*)&rel,
      (void*)&pre_enc, (void*)&pre0, (void*)&hsW0,
      (void*)&W_hh0, (void*)&W_ih1, (void*)&W_hh1, (void*)&W_att_dec,
      (void*)&W_lin_dec, (void*)&gvec, (void*)&hlens,
      (void*)&b_ih0, (void*)&b_hh0, (void*)&b_ih1, (void*)&b_hh1,
      (void*)&hdec_p
    };
    hipLaunchCooperativeKernel((const void*)scan_k, dim3(NBLK), dim3(256),
                               args, 0, stream);
  }

  // P = tanh(henc+hdec) bf16
  pack_k<<<(B_*T_*U_*512/8 + 255)/256, 256, 0, stream>>>(henc, hdec_p, Pbf);
  joint_mfma_k<<<8000, 256, 0, stream>>>(Pbf, Wbf, b_lin_out, out);
}